// Round 5
// baseline (544.623 us; speedup 1.0000x reference)
//
#include <hip/hip_runtime.h>

#define N 4096
#define D 512
#define BIG 1e30f
#define CMAX 2048
#define CMAX2 1024
#define CMAX3 512
#define NW (N / 32)

typedef unsigned long long u64;
typedef unsigned short u16;
typedef _Float16 f16x8 __attribute__((ext_vector_type(8)));
typedef float floatx4 __attribute__((ext_vector_type(4)));

// ---------------- fused prep: f32->f16 convert + row sq-norms + repr partial + init
__global__ __launch_bounds__(256) void prep_kernel(const float* __restrict__ x1,
                                                   const float* __restrict__ x2,
                                                   u16* __restrict__ h1,
                                                   u16* __restrict__ h2,
                                                   float* __restrict__ sq,
                                                   float* __restrict__ accumArr,
                                                   int* __restrict__ comp,
                                                   u64* __restrict__ compBest,
                                                   int* __restrict__ comp_c,
                                                   int* __restrict__ doneFlag) {
    const int tid = blockIdx.x * 256 + threadIdx.x;
    if (tid < 2 * N) {
        comp[tid] = tid & (N - 1);
        compBest[tid] = ~0ull;
    }
    if (tid < 2 * CMAX) comp_c[tid] = tid & (CMAX - 1);
    if (tid == 0) doneFlag[0] = 0;

    const int wave = threadIdx.x >> 6, lane = threadIdx.x & 63;
    const int row = blockIdx.x * 4 + wave;
    const float4* r1 = (const float4*)(x1 + (size_t)row * D);
    const float4* r2 = (const float4*)(x2 + (size_t)row * D);
    float4 a0 = r1[lane * 2], a1 = r1[lane * 2 + 1];
    float4 b0 = r2[lane * 2], b1 = r2[lane * 2 + 1];
    ushort4* o1 = (ushort4*)(h1 + (size_t)row * D + lane * 8);
    ushort4* o2 = (ushort4*)(h2 + (size_t)row * D + lane * 8);
    o1[0] = make_ushort4(__builtin_bit_cast(u16, (_Float16)a0.x), __builtin_bit_cast(u16, (_Float16)a0.y),
                         __builtin_bit_cast(u16, (_Float16)a0.z), __builtin_bit_cast(u16, (_Float16)a0.w));
    o1[1] = make_ushort4(__builtin_bit_cast(u16, (_Float16)a1.x), __builtin_bit_cast(u16, (_Float16)a1.y),
                         __builtin_bit_cast(u16, (_Float16)a1.z), __builtin_bit_cast(u16, (_Float16)a1.w));
    o2[0] = make_ushort4(__builtin_bit_cast(u16, (_Float16)b0.x), __builtin_bit_cast(u16, (_Float16)b0.y),
                         __builtin_bit_cast(u16, (_Float16)b0.z), __builtin_bit_cast(u16, (_Float16)b0.w));
    o2[1] = make_ushort4(__builtin_bit_cast(u16, (_Float16)b1.x), __builtin_bit_cast(u16, (_Float16)b1.y),
                         __builtin_bit_cast(u16, (_Float16)b1.z), __builtin_bit_cast(u16, (_Float16)b1.w));
    float s1 = 0.f, s2 = 0.f, sr = 0.f;
    float av[8] = {a0.x, a0.y, a0.z, a0.w, a1.x, a1.y, a1.z, a1.w};
    float bv[8] = {b0.x, b0.y, b0.z, b0.w, b1.x, b1.y, b1.z, b1.w};
#pragma unroll
    for (int e = 0; e < 8; ++e) {
        s1 = fmaf(av[e], av[e], s1);
        s2 = fmaf(bv[e], bv[e], s2);
        float d = av[e] - bv[e];
        sr = fmaf(d, d, sr);
    }
#pragma unroll
    for (int off = 32; off > 0; off >>= 1) {
        s1 += __shfl_down(s1, off, 64);
        s2 += __shfl_down(s2, off, 64);
        sr += __shfl_down(sr, off, 64);
    }
    __shared__ float wsr[4];
    if (lane == 0) {
        sq[row] = s1;
        sq[N + row] = s2;
        wsr[wave] = sr;
    }
    __syncthreads();
    if (threadIdx.x == 0)
        accumArr[blockIdx.x] = wsr[0] + wsr[1] + wsr[2] + wsr[3];
}

// ---------------- single-pass f16 MFMA GEMM + dist epilogue + fused round-1 row argmin
// SYMMETRIC triangle compute+store; DOUBLE-BUFFERED K-loop; LDS chunk-XOR swizzle
// (chunk' = chunk ^ ((row>>1)&3)) applied on the GLOBAL source (rule #21) and the
// fragment read -> ds_read_b128 bank-granule spreads over all 8 groups (2-way, free).
#define BM 128
#define BN 128
#define BK 32
#define NB (N / BM)          // 32 tile rows/cols
#define NPAIR (NB * (NB + 1) / 2)  // 528
#define NT (D / BK)          // 16

__global__ __launch_bounds__(256) void gemm_dist_sym_kernel(const u16* __restrict__ h1,
                                                            const u16* __restrict__ h2,
                                                            const float* __restrict__ sqn,
                                                            float* __restrict__ dist1,
                                                            float* __restrict__ dist2,
                                                            u64* __restrict__ compBest) {
    const int m = blockIdx.z;
    const u16* H = m ? h2 : h1;
    const float* SQ = sqn + (size_t)m * N;
    float* dist = m ? dist2 : dist1;
    u64* cb = compBest + (size_t)m * N;

    // decode linear pair index -> (by, bx), by <= bx
    const int t = blockIdx.x;
    int by = (int)((65.0f - sqrtf(4225.0f - 8.0f * (float)t)) * 0.5f);
    while (by > 0 && by * 32 - by * (by - 1) / 2 > t) --by;
    while ((by + 1) * 32 - (by + 1) * by / 2 <= t) ++by;
    const int bx = by + (t - (by * 32 - by * (by - 1) / 2));
    const bool diag = (by == bx);

    __shared__ u16 SH[4 * BM * BK];          // 32 KB: two (A,B) buffers
    u16* A0 = SH;
    u16* B0 = SH + BM * BK;
    u16* A1 = SH + 2 * BM * BK;
    u16* B1 = SH + 3 * BM * BK;

    const int tid = threadIdx.x;
    const int wave = tid >> 6, lane = tid & 63;
    const int wm = wave >> 1, wn = wave & 1;
    const int row0 = by * BM, col0 = bx * BN;

    floatx4 acc[4][4] = {};

    const int srow = lane >> 2;
    // swizzled source chunk: chunk' = (lane&3) ^ ((srow>>1)&3) = (lane&3) ^ ((lane>>3)&3)
    const int scol = (((lane & 3) ^ ((lane >> 3) & 3))) * 8;

#define STAGE(AB, BB, K0)                                                                      \
    {                                                                                          \
        _Pragma("unroll") for (int i_ = 0; i_ < 2; ++i_) {                                     \
            const int rb_ = wave * 32 + i_ * 16;                                               \
            const u16* ga_ = H + (size_t)(row0 + rb_ + srow) * D + (K0) + scol;                \
            __builtin_amdgcn_global_load_lds(                                                  \
                (const __attribute__((address_space(1))) unsigned int*)ga_,                    \
                (__attribute__((address_space(3))) unsigned int*)&(AB)[rb_ * BK], 16, 0, 0);   \
            if (!diag) {                                                                       \
                const u16* gb_ = H + (size_t)(col0 + rb_ + srow) * D + (K0) + scol;            \
                __builtin_amdgcn_global_load_lds(                                              \
                    (const __attribute__((address_space(1))) unsigned int*)gb_,                \
                    (__attribute__((address_space(3))) unsigned int*)&(BB)[rb_ * BK], 16, 0, 0); \
            }                                                                                  \
        }                                                                                      \
    }

    STAGE(A0, B0, 0);
    __syncthreads();           // buf0 landed

    // swizzled read chunk for fragment row fm = lane&15: cs = (gc ^ ((fm>>1)&3))*8
    const int cs = (((lane >> 4) ^ ((lane >> 1) & 3))) * 8;
    const int fm = lane & 15;
#pragma unroll 2
    for (int kt = 0; kt < NT; ++kt) {
        u16* Ac = (kt & 1) ? A1 : A0;
        u16* Bc = (kt & 1) ? B1 : B0;
        if (kt + 1 < NT) {
            u16* An = (kt & 1) ? A0 : A1;
            u16* Bn = (kt & 1) ? B0 : B1;
            STAGE(An, Bn, (kt + 1) * BK);
        }
        const u16* Bs = diag ? Ac : Bc;
        f16x8 a8[4], b8[4];
#pragma unroll
        for (int s = 0; s < 4; ++s) {
            a8[s] = *(const f16x8*)&Ac[(wm * 64 + s * 16 + fm) * BK + cs];
            b8[s] = *(const f16x8*)&Bs[(wn * 64 + s * 16 + fm) * BK + cs];
        }
#pragma unroll
        for (int i = 0; i < 4; ++i)
#pragma unroll
            for (int j = 0; j < 4; ++j)
                acc[i][j] = __builtin_amdgcn_mfma_f32_16x16x32_f16(a8[i], b8[j], acc[i][j], 0, 0, 0);
        __syncthreads();       // drains staged loads; protects buffer reuse
    }
#undef STAGE

    float* Cs = (float*)SH + wave * 1024;

    const int lr = lane & 15;
    const int lq = lane >> 4;
    float sc[4];
#pragma unroll
    for (int ns = 0; ns < 4; ++ns) sc[ns] = SQ[col0 + wn * 64 + ns * 16 + lr];
    u64 colBest[4] = {~0ull, ~0ull, ~0ull, ~0ull};
#pragma unroll
    for (int ms = 0; ms < 4; ++ms) {
        const int rb = row0 + wm * 64 + ms * 16 + lq * 4;
        float srow_[4];
#pragma unroll
        for (int r = 0; r < 4; ++r) srow_[r] = SQ[rb + r];
#pragma unroll
        for (int r = 0; r < 4; ++r) {
            const int row = rb + r;
            float dval[4];
#pragma unroll
            for (int ns = 0; ns < 4; ++ns) {
                const int col = col0 + wn * 64 + ns * 16 + lr;
                float d2 = srow_[r] + sc[ns] - 2.0f * acc[ms][ns][r];
                dval[ns] = (row == col) ? BIG : sqrtf(fmaxf(d2, 1e-12f));
            }
            float vmin = fminf(fminf(dval[0], dval[1]), fminf(dval[2], dval[3]));
            int nsel = (dval[0] == vmin) ? 0 : (dval[1] == vmin) ? 1 : (dval[2] == vmin) ? 2 : 3;
            u64 pmin = (((u64)__float_as_uint(vmin)) << 32) | (unsigned)(col0 + wn * 64 + nsel * 16 + lr);
#pragma unroll
            for (int msk = 1; msk < 16; msk <<= 1) {
                u64 o = __shfl_xor(pmin, msk, 64);
                pmin = o < pmin ? o : pmin;
            }
            if (lr == 0) atomicMin(&cb[row], pmin);
            if (!diag) {
#pragma unroll
                for (int ns = 0; ns < 4; ++ns) {
                    u64 p = (((u64)__float_as_uint(dval[ns])) << 32) | (unsigned)row;
                    colBest[ns] = p < colBest[ns] ? p : colBest[ns];
                }
            }
#pragma unroll
            for (int ns = 0; ns < 4; ++ns)
                Cs[(lq * 4 + r) * 64 + ns * 16 + lr] = dval[ns];
        }
        // triangle tile store only (rows of dist)
#pragma unroll
        for (int p = 0; p < 4; ++p) {
            float4 v4 = *(float4*)&Cs[p * 256 + lane * 4];
            const int gr = row0 + wm * 64 + ms * 16 + p * 4 + (lane >> 4);
            const int gc = col0 + wn * 64 + (lane & 15) * 4;
            *(float4*)&dist[(size_t)gr * N + gc] = v4;
        }
    }
    // column argmin -> compBest for the mirror rows (off-diagonal only)
    if (!diag) {
#pragma unroll
        for (int ns = 0; ns < 4; ++ns) {
            u64 b = colBest[ns];
            u64 o = __shfl_xor(b, 16, 64);
            b = o < b ? o : b;
            o = __shfl_xor(b, 32, 64);
            b = o < b ? o : b;
            if (lq == 0) atomicMin(&cb[col0 + wn * 64 + ns * 16 + lr], b);
        }
    }
}

// ---------------- merge round 1 + comp-grouped row list (for ownership contraction)
// distc init REMOVED: rowgroup_kernel owner-writes every cell that is later read.
__global__ __launch_bounds__(1024) void merge1i_kernel(int* __restrict__ comp,
                                                       u64* __restrict__ compBest,
                                                       float* __restrict__ deaths,
                                                       int* __restrict__ cnt,
                                                       int* __restrict__ numComp,
                                                       int* __restrict__ numC1,
                                                       int* __restrict__ rowStart,
                                                       int* __restrict__ rowlist) {
    const int t = threadIdx.x;
    const int m = blockIdx.x;
    int* cp = comp + (size_t)m * N;
    u64* cb = compBest + (size_t)m * N;
    float* dth = deaths + (size_t)m * N;
    int* rsG = rowStart + (size_t)m * (CMAX + 1);
    int* rlG = rowlist + (size_t)m * N;

    __shared__ int pa[N];
    __shared__ int pb[N];
    __shared__ unsigned flagbits[NW];
    __shared__ int wpc[NW];
    __shared__ int done;

    if (t == 0) cnt[m] = 0;
    __syncthreads();

    for (int c = t; c < N; c += 1024) {
        u64 best = cb[c];
        int p = c;
        if (best != ~0ull) {
            int j = (int)(unsigned)best;
            int c2 = cp[j];
            u64 best2 = cb[c2];
            int j2 = (int)(unsigned)best2;
            bool mutual = (cp[j2] == c);
            if (!(mutual && c < c2)) {
                p = c2;
                int idx = atomicAdd(cnt + m, 1);
                dth[idx] = __uint_as_float((unsigned)(best >> 32));
            }
        }
        pa[c] = p;
    }

    int* A = pa;
    int* B = pb;
    while (true) {
        __syncthreads();
        if (t == 0) done = 1;
        __syncthreads();
        bool ch = false;
        for (int c = t; c < N; c += 1024) {
            int g = A[A[c]];
            B[c] = g;
            ch |= (g != A[c]);
        }
        if (ch) done = 0;
        __syncthreads();
        int* tmp = A; A = B; B = tmp;
        if (done) break;
    }

    for (int w = t; w < NW; w += 1024) flagbits[w] = 0u;
    __syncthreads();
    for (int i = t; i < N; i += 1024)
        atomicOr(&flagbits[A[i] >> 5], 1u << (A[i] & 31));
    __syncthreads();
    if (t < NW) wpc[t] = __popc(flagbits[t]);
    __syncthreads();
    for (int off = 1; off < NW; off <<= 1) {
        int v = 0;
        if (t < NW) v = wpc[t] + ((t >= off) ? wpc[t - off] : 0);
        __syncthreads();
        if (t < NW) wpc[t] = v;
        __syncthreads();
    }
    for (int i = t; i < N; i += 1024) {
        int root = A[i];
        int w = root >> 5, b = root & 31;
        int base = w ? wpc[w - 1] : 0;
        unsigned mask = b ? ((1u << b) - 1u) : 0u;
        cp[i] = base + __popc(flagbits[w] & mask);
    }
    for (int c = t; c < N; c += 1024) cb[c] = ~0ull;
    if (t == 0) {
        int C1 = wpc[NW - 1];
        numC1[m] = C1;
        numComp[m] = C1;
    }
    __syncthreads();

    // ---- build comp-grouped row list: histogram + inclusive scan + scatter
    // (cp[] global writes are visible after __syncthreads: compiler drains vmcnt
    // before s_barrier; same-CU L1 serves the reload.)
    int* X = pb;   // histogram / scan ping
    int* Y = pa;   // scan pong / offsets
    for (int c = t; c < CMAX; c += 1024) X[c] = 0;
    __syncthreads();
    for (int i = t; i < N; i += 1024) atomicAdd(&X[cp[i]], 1);
    __syncthreads();
    for (int off = 1; off < CMAX; off <<= 1) {
        for (int c = t; c < CMAX; c += 1024)
            Y[c] = X[c] + ((c >= off) ? X[c - off] : 0);
        __syncthreads();
        int* tmp = X; X = Y; Y = tmp;
    }
    // X = inclusive scan; exclusive offsets into Y + global rowStart
    for (int c = t; c < CMAX; c += 1024) {
        int ex = c ? X[c - 1] : 0;
        Y[c] = ex;
        rsG[c] = ex;
    }
    if (t == 0) rsG[CMAX] = N;
    __syncthreads();
    for (int i = t; i < N; i += 1024) {
        int pos = atomicAdd(&Y[cp[i]], 1);
        rlG[pos] = i;
    }
}

// ---------------- OWNERSHIP level-1 contraction: one block per component.
// Min-accumulates all rows of comp r into LDS bins, then PLAIN-stores distc row r
// (no global atomics, no distc init). Triangle reads as before (row from its
// diagonal tile onward); symscan completes the symmetrization.
__global__ __launch_bounds__(256) void rowgroup_kernel(const float* __restrict__ dist1,
                                                       const float* __restrict__ dist2,
                                                       const int* __restrict__ comp,
                                                       const int* __restrict__ rowlist,
                                                       const int* __restrict__ rowStart,
                                                       const int* __restrict__ numC1,
                                                       unsigned* __restrict__ distc_u) {
    const int m = blockIdx.y;
    const int C1 = numC1[m];
    const int r = blockIdx.x;
    if (r >= C1) return;
    const int cend = (C1 + 63) & ~63;   // symscan reads tiles up to ceil64(C1)
    const float* dist = m ? dist2 : dist1;
    const int* cp = comp + (size_t)m * N;
    const int4* cp4 = (const int4*)cp;
    const int* rl = rowlist + (size_t)m * N;
    const int* rs = rowStart + (size_t)m * (CMAX + 1);
    const int s0 = rs[r], s1 = rs[r + 1];
    __shared__ unsigned bins[CMAX];
    const int t = threadIdx.x;
    for (int b = t; b < cend; b += 256) bins[b] = 0x7f800000u;
    __syncthreads();
    for (int ri = s0; ri < s1; ++ri) {
        const int i = rl[ri];
        const float4* row4 = (const float4*)(dist + (size_t)i * N);
        const int q0 = (i >> 7) << 5;   // float4 index of this row's diagonal-tile start
        for (int q = q0 + t; q < N / 4; q += 256) {
            float4 v = row4[q];
            int4 cj = cp4[q];
            atomicMin(&bins[cj.x], __float_as_uint(v.x));
            atomicMin(&bins[cj.y], __float_as_uint(v.y));
            atomicMin(&bins[cj.z], __float_as_uint(v.z));
            atomicMin(&bins[cj.w], __float_as_uint(v.w));
        }
    }
    __syncthreads();
    unsigned* drow = distc_u + ((size_t)m * CMAX + r) * CMAX;
    for (int b = t; b < cend; b += 256) drow[b] = bins[b];
}

// ---------------- FUSED symmetrize + round-2 scan + distc2 init
#define CT 64
#define NCT (CMAX / CT)                // 32
#define NPAIRC (NCT * (NCT + 1) / 2)   // 528
__global__ __launch_bounds__(256) void symscan_kernel(unsigned* __restrict__ distc_u,
                                                      u64* __restrict__ compBest,
                                                      const int* __restrict__ numComp,
                                                      const int* __restrict__ numC1,
                                                      unsigned* __restrict__ distc2_u) {
    const int tid = threadIdx.x;
    if (blockIdx.x >= NPAIRC) {
        // init distc2: 2*CMAX2*CMAX2 floats = 524,288 uint4; (256 blocks x 2 y) x 256 thr x 4
        const size_t base = ((size_t)blockIdx.y * 256 + (blockIdx.x - NPAIRC)) * 256 + tid;
        uint4 v = make_uint4(0x7f800000u, 0x7f800000u, 0x7f800000u, 0x7f800000u);
#pragma unroll
        for (int k = 0; k < 4; ++k)
            ((uint4*)distc2_u)[base + (size_t)k * 131072] = v;
        return;
    }
    const int m = blockIdx.y;
    if (numComp[m] <= 1) return;
    const int C1 = numC1[m];
    const int t = blockIdx.x;
    int a = (int)((65.0f - sqrtf(4225.0f - 8.0f * (float)t)) * 0.5f);
    while (a > 0 && a * 32 - a * (a - 1) / 2 > t) --a;
    while ((a + 1) * 32 - (a + 1) * a / 2 <= t) ++a;
    const int b = a + (t - (a * 32 - a * (a - 1) / 2));
    if (a * CT >= C1 || b * CT >= C1) return;   // all-inf region, never read downstream

    unsigned* Dm = distc_u + (size_t)m * CMAX * CMAX;
    unsigned* P = Dm + (size_t)(a * CT) * CMAX + b * CT;   // tile (a,b)
    unsigned* Q = Dm + (size_t)(b * CT) * CMAX + a * CT;   // tile (b,a)
    u64* cb = compBest + (size_t)m * N;

    __shared__ float L[CT][CT + 1];
    __shared__ float M[CT][CT + 1];
#pragma unroll
    for (int e0 = 0; e0 < 4; ++e0) {
        int e = e0 * 256 + tid;
        int r = e >> 4, c4 = (e & 15) << 2;
        float4 v = *(const float4*)&Q[(size_t)r * CMAX + c4];
        L[r][c4] = v.x; L[r][c4 + 1] = v.y; L[r][c4 + 2] = v.z; L[r][c4 + 3] = v.w;
    }
    __syncthreads();
#pragma unroll
    for (int e0 = 0; e0 < 4; ++e0) {
        int e = e0 * 256 + tid;
        int r = e >> 4, c4 = (e & 15) << 2;
        float4 v = *(const float4*)&P[(size_t)r * CMAX + c4];
        float4 f;
        f.x = fminf(v.x, L[c4 + 0][r]);
        f.y = fminf(v.y, L[c4 + 1][r]);
        f.z = fminf(v.z, L[c4 + 2][r]);
        f.w = fminf(v.w, L[c4 + 3][r]);
        *(float4*)&P[(size_t)r * CMAX + c4] = f;
        M[r][c4] = f.x; M[r][c4 + 1] = f.y; M[r][c4 + 2] = f.z; M[r][c4 + 3] = f.w;
    }
    __syncthreads();

    // direction 1: rows of tile a over cols of tile b (S rows)
    {
        const int rloc = tid >> 2;
        const int r = a * CT + rloc;
        const int c0 = (tid & 3) * 16;
        u64 best = ~0ull;
#pragma unroll
        for (int c = 0; c < 16; ++c) {
            const int j = b * CT + c0 + c;
            const unsigned bits = __float_as_uint(M[rloc][c0 + c]);
            if (j < C1 && j != r && bits < 0x7f800000u) {
                u64 p = (((u64)bits) << 32) | (unsigned)j;
                best = p < best ? p : best;
            }
        }
        u64 o = __shfl_xor(best, 1, 64); best = o < best ? o : best;
        o = __shfl_xor(best, 2, 64); best = o < best ? o : best;
        if ((tid & 3) == 0 && r < C1 && best != ~0ull) atomicMin(&cb[r], best);
    }

    if (a == b) return;

    // direction 2: rows of tile b over cols of tile a (S^T = M columns)
    {
        const int rloc = tid >> 2;
        const int r = b * CT + rloc;
        const int c0 = (tid & 3) * 16;
        u64 best = ~0ull;
#pragma unroll
        for (int c = 0; c < 16; ++c) {
            const int j = a * CT + c0 + c;
            const unsigned bits = __float_as_uint(M[c0 + c][rloc]);
            if (j < C1 && bits < 0x7f800000u) {   // j != r guaranteed (a != b)
                u64 p = (((u64)bits) << 32) | (unsigned)j;
                best = p < best ? p : best;
            }
        }
        u64 o = __shfl_xor(best, 1, 64); best = o < best ? o : best;
        o = __shfl_xor(best, 2, 64); best = o < best ? o : best;
        if ((tid & 3) == 0 && r < C1 && best != ~0ull) atomicMin(&cb[r], best);
    }

    // write back S^T to tile (b,a)
#pragma unroll
    for (int e0 = 0; e0 < 4; ++e0) {
        int e = e0 * 256 + tid;
        int r = e >> 4, c4 = (e & 15) << 2;
        float4 f;
        f.x = M[c4 + 0][r];
        f.y = M[c4 + 1][r];
        f.z = M[c4 + 2][r];
        f.w = M[c4 + 3][r];
        *(float4*)&Q[(size_t)r * CMAX + c4] = f;
    }
}

// ---------------- merge round 2 (trimmed): hook + jump + dense relabel + comp_c2 identity
__global__ __launch_bounds__(1024) void merge2_kernel(int* __restrict__ comp_c,
                                                      u64* __restrict__ compBest,
                                                      float* __restrict__ deaths,
                                                      int* __restrict__ cnt,
                                                      int* __restrict__ numComp,
                                                      const int* __restrict__ numC1,
                                                      int* __restrict__ numC2,
                                                      int* __restrict__ comp_c2) {
    const int m = blockIdx.x;
    const int t = threadIdx.x;
    const int C1 = numC1[m];
    int* cc2i = comp_c2 + (size_t)m * CMAX2;
    for (int c = t; c < CMAX2; c += 1024) cc2i[c] = c;
    if (numComp[m] <= 1) {
        if (t == 0) numC2[m] = numComp[m];
        return;
    }
    int* cc = comp_c + (size_t)m * CMAX;
    u64* cb = compBest + (size_t)m * N;
    float* dth = deaths + (size_t)m * N;

    __shared__ int pa[CMAX];
    __shared__ int pb[CMAX];
    __shared__ unsigned flagbits[CMAX / 32];
    __shared__ int wpc[CMAX / 32];
    __shared__ int done;

    for (int c = t; c < C1; c += 1024) {
        u64 best = cb[c];
        int p = c;
        if (best != ~0ull) {
            int j = (int)(unsigned)best;
            int c2 = cc[j];
            u64 best2 = cb[c2];
            int j2 = (int)(unsigned)best2;
            bool mutual = (cc[j2] == c);
            if (!(mutual && c < c2)) {
                p = c2;
                int idx = atomicAdd(cnt + m, 1);
                dth[idx] = __uint_as_float((unsigned)(best >> 32));
            }
        }
        pa[c] = p;
    }

    int* A = pa;
    int* B = pb;
    while (true) {
        __syncthreads();
        if (t == 0) done = 1;
        __syncthreads();
        bool ch = false;
        for (int c = t; c < C1; c += 1024) {
            int g = A[A[c]];
            B[c] = g;
            ch |= (g != A[c]);
        }
        if (ch) done = 0;
        __syncthreads();
        int* tmp = A; A = B; B = tmp;
        if (done) break;
    }

    for (int w = t; w < CMAX / 32; w += 1024) flagbits[w] = 0u;
    __syncthreads();
    for (int j = t; j < C1; j += 1024)
        atomicOr(&flagbits[A[j] >> 5], 1u << (A[j] & 31));
    __syncthreads();
    if (t < CMAX / 32) wpc[t] = __popc(flagbits[t]);
    __syncthreads();
    for (int off = 1; off < CMAX / 32; off <<= 1) {
        int v = 0;
        if (t < CMAX / 32) v = wpc[t] + ((t >= off) ? wpc[t - off] : 0);
        __syncthreads();
        if (t < CMAX / 32) wpc[t] = v;
        __syncthreads();
    }
    for (int j = t; j < C1; j += 1024) {
        int root = A[j];
        int w = root >> 5, b = root & 31;
        int base = w ? wpc[w - 1] : 0;
        unsigned mask = b ? ((1u << b) - 1u) : 0u;
        cc[j] = base + __popc(flagbits[w] & mask);
    }
    for (int c = t; c < C1; c += 1024) cb[c] = ~0ull;
    if (t == 0) {
        int C2 = wpc[CMAX / 32 - 1];
        numC2[m] = C2;
        numComp[m] = C2;
    }
}

// ---------------- atomic level-2 contraction: row of distc -> bins[C2] -> distc2
__global__ __launch_bounds__(256) void rowatomic2_kernel(const float* __restrict__ distc,
                                                         const int* __restrict__ comp_c,
                                                         const int* __restrict__ numComp,
                                                         const int* __restrict__ numC1,
                                                         unsigned* __restrict__ distc2_u) {
    const int m = blockIdx.y;
    if (numComp[m] <= 1) return;
    const int C1 = numC1[m];
    const int r = blockIdx.x;
    if (r >= C1) return;
    const int* cc = comp_c + (size_t)m * CMAX;
    const float* row = distc + ((size_t)m * CMAX + r) * CMAX;
    __shared__ unsigned bins[CMAX2];
    const int t = threadIdx.x;
    for (int b = t; b < CMAX2; b += 256) bins[b] = 0x7f800000u;
    __syncthreads();
    for (int j = t; j < C1; j += 256)
        atomicMin(&bins[cc[j]], __float_as_uint(row[j]));
    __syncthreads();
    unsigned* drow = distc2_u + ((size_t)m * CMAX2 + cc[r]) * CMAX2;
    for (int b = t; b < CMAX2; b += 256) {
        unsigned v = bins[b];
        if (v != 0x7f800000u) atomicMin(&drow[b], v);
    }
}

// ---------------- level-3 scan over distc2 (blocks < 2*CMAX2) + distc3 +inf init (rest)
__global__ __launch_bounds__(256) void scan3_kernel(const float* __restrict__ distc2,
                                                    const int* __restrict__ comp_c2,
                                                    u64* __restrict__ compBest,
                                                    const int* __restrict__ numComp,
                                                    const int* __restrict__ numC2,
                                                    unsigned* __restrict__ distc3_u) {
    const int t = threadIdx.x;
    if (blockIdx.x >= 2 * CMAX2) {
        // init distc3: 2*512*512 floats = 131072 uint4; 256 blocks x 256 thr x 2
        const size_t idx = (size_t)(blockIdx.x - 2 * CMAX2) * 256 + t;
        uint4 v = make_uint4(0x7f800000u, 0x7f800000u, 0x7f800000u, 0x7f800000u);
        ((uint4*)distc3_u)[idx] = v;
        ((uint4*)distc3_u)[idx + 65536] = v;
        return;
    }
    const int m = blockIdx.x >> 10;          // CMAX2 = 1024
    if (numComp[m] <= 1) return;
    const int C2 = numC2[m];
    const int r = blockIdx.x & (CMAX2 - 1);
    if (r >= C2) return;
    const int* cc = comp_c2 + (size_t)m * CMAX2;
    u64* cb = compBest + (size_t)m * N;
    const int myc = cc[r];
    const float4* row4 = (const float4*)(distc2 + ((size_t)m * CMAX2 + r) * CMAX2);
    const int4* cc4 = (const int4*)cc;
    float4 v = row4[t];
    int4 cj = cc4[t];
    int j0 = t * 4;
    u64 p0 = (j0 + 0 < C2 && cj.x != myc) ? ((((u64)__float_as_uint(v.x)) << 32) | (unsigned)(j0 + 0)) : ~0ull;
    u64 p1 = (j0 + 1 < C2 && cj.y != myc) ? ((((u64)__float_as_uint(v.y)) << 32) | (unsigned)(j0 + 1)) : ~0ull;
    u64 p2 = (j0 + 2 < C2 && cj.z != myc) ? ((((u64)__float_as_uint(v.z)) << 32) | (unsigned)(j0 + 2)) : ~0ull;
    u64 p3 = (j0 + 3 < C2 && cj.w != myc) ? ((((u64)__float_as_uint(v.w)) << 32) | (unsigned)(j0 + 3)) : ~0ull;
    u64 q0 = p0 < p1 ? p0 : p1;
    u64 q1 = p2 < p3 ? p2 : p3;
    u64 best = q0 < q1 ? q0 : q1;
#pragma unroll
    for (int off = 32; off > 0; off >>= 1) {
        u64 o = __shfl_down(best, off, 64);
        best = o < best ? o : best;
    }
    if ((t & 63) == 0) atomicMin(cb + myc, best);
}

// ---------------- merge round 3: hook + jump + dense relabel of comp_c2
__global__ __launch_bounds__(1024) void merge3_kernel(int* __restrict__ comp_c2,
                                                      u64* __restrict__ compBest,
                                                      float* __restrict__ deaths,
                                                      int* __restrict__ cnt,
                                                      int* __restrict__ numComp,
                                                      const int* __restrict__ numC2,
                                                      int* __restrict__ numC3) {
    const int m = blockIdx.x;
    const int t = threadIdx.x;
    if (numComp[m] <= 1) {
        if (t == 0) numC3[m] = numComp[m];
        return;
    }
    const int C2 = numC2[m];
    int* cc = comp_c2 + (size_t)m * CMAX2;
    u64* cb = compBest + (size_t)m * N;
    float* dth = deaths + (size_t)m * N;

    __shared__ int pa[CMAX2];
    __shared__ int pb[CMAX2];
    __shared__ unsigned flagbits[CMAX2 / 32];
    __shared__ int wpc[CMAX2 / 32];
    __shared__ int done;

    for (int c = t; c < C2; c += 1024) {
        u64 best = cb[c];
        int p = c;
        if (best != ~0ull) {
            int j = (int)(unsigned)best;
            int c2 = cc[j];
            u64 best2 = cb[c2];
            int j2 = (int)(unsigned)best2;
            bool mutual = (cc[j2] == c);
            if (!(mutual && c < c2)) {
                p = c2;
                int idx = atomicAdd(cnt + m, 1);
                dth[idx] = __uint_as_float((unsigned)(best >> 32));
            }
        }
        pa[c] = p;
    }

    int* A = pa;
    int* B = pb;
    while (true) {
        __syncthreads();
        if (t == 0) done = 1;
        __syncthreads();
        bool ch = false;
        for (int c = t; c < C2; c += 1024) {
            int g = A[A[c]];
            B[c] = g;
            ch |= (g != A[c]);
        }
        if (ch) done = 0;
        __syncthreads();
        int* tmp = A; A = B; B = tmp;
        if (done) break;
    }

    for (int w = t; w < CMAX2 / 32; w += 1024) flagbits[w] = 0u;
    __syncthreads();
    for (int j = t; j < C2; j += 1024)
        atomicOr(&flagbits[A[j] >> 5], 1u << (A[j] & 31));
    __syncthreads();
    if (t < CMAX2 / 32) wpc[t] = __popc(flagbits[t]);
    __syncthreads();
    for (int off = 1; off < CMAX2 / 32; off <<= 1) {
        int v = 0;
        if (t < CMAX2 / 32) v = wpc[t] + ((t >= off) ? wpc[t - off] : 0);
        __syncthreads();
        if (t < CMAX2 / 32) wpc[t] = v;
        __syncthreads();
    }
    for (int j = t; j < C2; j += 1024) {
        int root = A[j];
        int w = root >> 5, b = root & 31;
        int base = w ? wpc[w - 1] : 0;
        unsigned mask = b ? ((1u << b) - 1u) : 0u;
        cc[j] = base + __popc(flagbits[w] & mask);
    }
    for (int c = t; c < C2; c += 1024) cb[c] = ~0ull;
    if (t == 0) {
        int C3 = wpc[CMAX2 / 32 - 1];
        numC3[m] = C3;
        numComp[m] = C3;
    }
}

// ---------------- atomic level-3 contraction: row of distc2 -> bins[C3] -> distc3
__global__ __launch_bounds__(256) void rowatomic3_kernel(const float* __restrict__ distc2,
                                                         const int* __restrict__ comp_c2,
                                                         const int* __restrict__ numComp,
                                                         const int* __restrict__ numC2,
                                                         unsigned* __restrict__ distc3_u) {
    const int m = blockIdx.y;
    if (numComp[m] <= 1) return;
    const int C2 = numC2[m];
    const int r = blockIdx.x;
    if (r >= C2) return;
    const int* cc = comp_c2 + (size_t)m * CMAX2;
    const float* row = distc2 + ((size_t)m * CMAX2 + r) * CMAX2;
    __shared__ unsigned bins[CMAX3];
    const int t = threadIdx.x;
    for (int b = t; b < CMAX3; b += 256) bins[b] = 0x7f800000u;
    __syncthreads();
    for (int j = t; j < C2; j += 256)
        atomicMin(&bins[cc[j]], __float_as_uint(row[j]));
    __syncthreads();
    unsigned* drow = distc3_u + ((size_t)m * CMAX3 + cc[r]) * CMAX3;
    for (int b = t; b < CMAX3; b += 256) {
        unsigned v = bins[b];
        if (v != 0x7f800000u) atomicMin(&drow[b], v);
    }
}

// ---------------- finish: rounds >= 4 on distc3 + register-bitonic sort + fused final
__global__ __launch_bounds__(1024) void finish_kernel(const float* __restrict__ distc3,
                                                      float* __restrict__ deaths,
                                                      int* __restrict__ cnt,
                                                      int* __restrict__ numComp,
                                                      const int* __restrict__ numC3,
                                                      const float* __restrict__ accumArr,
                                                      int* __restrict__ doneFlag,
                                                      float* __restrict__ out) {
    const int m = blockIdx.x;
    int nc = numComp[m];
    const int C3 = numC3[m];
    const float* Dm = distc3 + (size_t)m * CMAX3 * CMAX3;
    float* dth = deaths + (size_t)m * N;
    const int t = threadIdx.x;
    const int wave = t >> 6, lane = t & 63;
    __shared__ int comp[CMAX3];
    __shared__ u64 cb[CMAX3];
    __shared__ int pa[CMAX3];
    __shared__ int pb[CMAX3];
    __shared__ unsigned flags[CMAX3 / 32];
    __shared__ int done, ncs, lastf;
    __shared__ float s[N];
    __shared__ float wsum[16];
    __shared__ float rsum[16];

    if (nc > 1) {
        for (int c = t; c < C3; c += 1024) {
            comp[c] = c;
            cb[c] = ~0ull;
        }
        __syncthreads();

        for (int round = 0; round < 10 && nc > 1; ++round) {
            for (int r = wave; r < C3; r += 16) {
                const int myc = comp[r];
                const float* row = Dm + (size_t)r * CMAX3;
                u64 best = ~0ull;
                for (int j = lane; j < C3; j += 64) {
                    if (comp[j] != myc) {
                        u64 p = (((u64)__float_as_uint(row[j])) << 32) | (unsigned)j;
                        best = p < best ? p : best;
                    }
                }
#pragma unroll
                for (int off = 32; off > 0; off >>= 1) {
                    u64 o = __shfl_down(best, off, 64);
                    best = o < best ? o : best;
                }
                if (lane == 0) atomicMin(&cb[myc], best);
            }
            __syncthreads();
            for (int c = t; c < C3; c += 1024) {
                u64 best = cb[c];
                int p = c;
                if (best != ~0ull) {
                    int j = (int)(unsigned)best;
                    int c2 = comp[j];
                    u64 best2 = cb[c2];
                    int j2 = (int)(unsigned)best2;
                    bool mutual = (comp[j2] == c);
                    if (!(mutual && c < c2)) {
                        p = c2;
                        int idx = atomicAdd(cnt + m, 1);
                        dth[idx] = __uint_as_float((unsigned)(best >> 32));
                    }
                }
                pa[c] = p;
            }
            int* A = pa; int* B = pb;
            while (true) {
                __syncthreads();
                if (t == 0) done = 1;
                __syncthreads();
                bool ch = false;
                for (int c = t; c < C3; c += 1024) {
                    int g = A[A[c]];
                    B[c] = g;
                    ch |= (g != A[c]);
                }
                if (ch) done = 0;
                __syncthreads();
                int* tmp = A; A = B; B = tmp;
                if (done) break;
            }
            for (int w = t; w < CMAX3 / 32; w += 1024) flags[w] = 0u;
            __syncthreads();
            for (int j = t; j < C3; j += 1024) {
                int root = A[comp[j]];
                comp[j] = root;
                atomicOr(&flags[root >> 5], 1u << (root & 31));
            }
            for (int c = t; c < C3; c += 1024) cb[c] = ~0ull;
            __syncthreads();
            if (t == 0) {
                int sacc = 0;
                for (int w = 0; w < CMAX3 / 32; ++w) sacc += __popc(flags[w]);
                ncs = sacc;
            }
            __syncthreads();
            nc = ncs;
        }
        if (t == 0) numComp[m] = nc;
    }
    __syncthreads();

    // ---- register-resident bitonic sort (ascending) of the 4096 deaths.
    const int t4 = t << 2;
    float v0, v1, v2, v3;
    {
        float4 l4 = *(const float4*)&dth[t4];
        v0 = l4.x; v1 = l4.y; v2 = l4.z; v3 = l4.w;
        if (t == 1023) v3 = BIG;   // element N-1 pad
    }
#define CSWAP(a, b, up)                         \
    {                                           \
        float mn_ = fminf(a, b), mx_ = fmaxf(a, b); \
        a = (up) ? mn_ : mx_;                   \
        b = (up) ? mx_ : mn_;                   \
    }
    for (int k = 2; k <= N; k <<= 1) {
        for (int jj = k >> 1; jj > 0; jj >>= 1) {
            if (jj >= 256) {
                s[t4] = v0; s[t4 + 1] = v1; s[t4 + 2] = v2; s[t4 + 3] = v3;
                __syncthreads();
                const bool up = ((t4 & k) == 0);
                const bool lower = ((t4 & jj) == 0);
                const bool mk = (up == lower);
                float o0 = s[t4 ^ jj], o1 = s[(t4 + 1) ^ jj];
                float o2 = s[(t4 + 2) ^ jj], o3 = s[(t4 + 3) ^ jj];
                v0 = mk ? fminf(v0, o0) : fmaxf(v0, o0);
                v1 = mk ? fminf(v1, o1) : fmaxf(v1, o1);
                v2 = mk ? fminf(v2, o2) : fmaxf(v2, o2);
                v3 = mk ? fminf(v3, o3) : fmaxf(v3, o3);
                __syncthreads();
            } else if (jj >= 4) {
                const int sl = jj >> 2;
                const bool up = ((t4 & k) == 0);
                const bool lower = ((lane & sl) == 0);
                const bool mk = (up == lower);
                float o0 = __shfl_xor(v0, sl, 64);
                float o1 = __shfl_xor(v1, sl, 64);
                float o2 = __shfl_xor(v2, sl, 64);
                float o3 = __shfl_xor(v3, sl, 64);
                v0 = mk ? fminf(v0, o0) : fmaxf(v0, o0);
                v1 = mk ? fminf(v1, o1) : fmaxf(v1, o1);
                v2 = mk ? fminf(v2, o2) : fmaxf(v2, o2);
                v3 = mk ? fminf(v3, o3) : fmaxf(v3, o3);
            } else if (jj == 2) {
                const bool up = ((t4 & k) == 0);
                CSWAP(v0, v2, up);
                CSWAP(v1, v3, up);
            } else {
                const bool u01 = ((t4 & k) == 0);
                const bool u23 = (((t4 + 2) & k) == 0);
                CSWAP(v0, v1, u01);
                CSWAP(v2, v3, u23);
            }
        }
    }
#undef CSWAP
    *(float4*)&dth[t4] = make_float4(v0, v1, v2, v3);

    // last-block fused final (device-scope ticket; grid-order independent)
    __threadfence();
    __syncthreads();
    if (t == 0) lastf = (atomicAdd(doneFlag, 1) == 1) ? 1 : 0;
    __syncthreads();
    if (!lastf) return;
    __threadfence();
    const float* s1 = deaths;
    const float* s2 = deaths + N;
    float sum = 0.f;
    for (int i = t; i < N - 1; i += 1024) {
        float a = s1[i], b = s2[i];
        sum += fminf(fabsf(a - b), 0.5f * (a + b));
    }
    float ra = accumArr[t];
#pragma unroll
    for (int off = 32; off > 0; off >>= 1) {
        sum += __shfl_down(sum, off, 64);
        ra += __shfl_down(ra, off, 64);
    }
    if (lane == 0) { wsum[wave] = sum; rsum[wave] = ra; }
    __syncthreads();
    if (t == 0) {
        float tot = 0.f, rt = 0.f;
        for (int k = 0; k < 16; ++k) { tot += wsum[k]; rt += rsum[k]; }
        out[0] = rt * (1.0f / ((float)N * (float)D)) + tot;
    }
}

extern "C" void kernel_launch(void* const* d_in, const int* in_sizes, int n_in,
                              void* d_out, int out_size, void* d_ws, size_t ws_size,
                              hipStream_t stream) {
    const float* x1 = (const float*)d_in[0];
    const float* x2 = (const float*)d_in[1];
    float* out = (float*)d_out;
    float* ws = (float*)d_ws;

    const size_t nn = (size_t)N * N;
    const size_t cc2 = (size_t)CMAX * CMAX;

    float* dist1 = ws;
    float* dist2 = ws + nn;
    float* distc = ws + 2 * nn;
    u16* h1 = (u16*)distc;                 // alias: dead before rowgroup owner-writes
    u16* h2 = h1 + (size_t)N * D;
    u64* compBest = (u64*)(distc + 2 * cc2);
    int* comp      = (int*)(compBest + 2 * N);
    int* comp_c    = comp + 2 * N;
    float* deaths  = (float*)(comp_c + 2 * CMAX);
    int* cnt       = (int*)(deaths + 2 * N);
    int* numComp   = cnt + 2;
    int* numC1     = numComp + 2;
    int* numC2     = numC1 + 2;
    int* numC3     = numC2 + 2;
    int* doneFlag  = numC3 + 2;
    float* sq      = (float*)(doneFlag + 2);
    float* accumArr = sq + 2 * N;          // 1024 floats
    int* rowStart  = (int*)(accumArr + 1024);       // 2*(CMAX+1) ints
    int* rowlist   = rowStart + 2 * (CMAX + 1);     // 2*N ints
    // level-2 buffers alias dist1 (dead after rowgroup) — distc2 init'd in symscan's
    // extra blocks, comp_c2 in merge2. Level-3 distc3 aliases distc (dead after
    // rowatomic2), init'd in scan3's extra blocks. NEVER earlier.
    float* distc2  = dist1;
    int* comp_c2   = (int*)(distc2 + 2 * (size_t)CMAX2 * CMAX2);
    float* distc3  = distc;

    prep_kernel<<<N / 4, 256, 0, stream>>>(x1, x2, h1, h2, sq, accumArr, comp, compBest,
                                           comp_c, doneFlag);
    gemm_dist_sym_kernel<<<dim3(NPAIR, 1, 2), 256, 0, stream>>>(h1, h2, sq, dist1, dist2, compBest);
    merge1i_kernel<<<2, 1024, 0, stream>>>(comp, compBest, deaths, cnt, numComp, numC1,
                                           rowStart, rowlist);
    rowgroup_kernel<<<dim3(CMAX, 2), 256, 0, stream>>>(dist1, dist2, comp, rowlist, rowStart,
                                                       numC1, (unsigned*)distc);
    symscan_kernel<<<dim3(NPAIRC + 256, 2), 256, 0, stream>>>((unsigned*)distc, compBest,
                                                              numComp, numC1, (unsigned*)distc2);
    merge2_kernel<<<2, 1024, 0, stream>>>(comp_c, compBest, deaths, cnt, numComp, numC1, numC2,
                                          comp_c2);
    rowatomic2_kernel<<<dim3(CMAX, 2), 256, 0, stream>>>(distc, comp_c, numComp, numC1,
                                                         (unsigned*)distc2);
    scan3_kernel<<<2 * CMAX2 + 256, 256, 0, stream>>>(distc2, comp_c2, compBest, numComp, numC2,
                                                      (unsigned*)distc3);
    merge3_kernel<<<2, 1024, 0, stream>>>(comp_c2, compBest, deaths, cnt, numComp, numC2, numC3);
    rowatomic3_kernel<<<dim3(CMAX2, 2), 256, 0, stream>>>(distc2, comp_c2, numComp, numC2,
                                                          (unsigned*)distc3);
    finish_kernel<<<2, 1024, 0, stream>>>(distc3, deaths, cnt, numComp, numC3,
                                          accumArr, doneFlag, out);
}

// Round 6
// 227.368 us; speedup vs baseline: 2.3953x; 2.3953x over previous
//
#include <hip/hip_runtime.h>

#define N 4096
#define D 512
#define BIG 1e30f
#define CMAX 2048
#define CMAX2 1024
#define CMAX3 512
#define NW (N / 32)

typedef unsigned long long u64;
typedef unsigned short u16;
typedef _Float16 f16x8 __attribute__((ext_vector_type(8)));
typedef float floatx4 __attribute__((ext_vector_type(4)));

// ---------------- fused prep: f32->f16 convert + row sq-norms + repr partial + init
__global__ __launch_bounds__(256) void prep_kernel(const float* __restrict__ x1,
                                                   const float* __restrict__ x2,
                                                   u16* __restrict__ h1,
                                                   u16* __restrict__ h2,
                                                   float* __restrict__ sq,
                                                   float* __restrict__ accumArr,
                                                   int* __restrict__ comp,
                                                   u64* __restrict__ compBest,
                                                   int* __restrict__ comp_c,
                                                   int* __restrict__ doneFlag) {
    const int tid = blockIdx.x * 256 + threadIdx.x;
    if (tid < 2 * N) {
        comp[tid] = tid & (N - 1);
        compBest[tid] = ~0ull;
    }
    if (tid < 2 * CMAX) comp_c[tid] = tid & (CMAX - 1);
    if (tid == 0) doneFlag[0] = 0;

    const int wave = threadIdx.x >> 6, lane = threadIdx.x & 63;
    const int row = blockIdx.x * 4 + wave;
    const float4* r1 = (const float4*)(x1 + (size_t)row * D);
    const float4* r2 = (const float4*)(x2 + (size_t)row * D);
    float4 a0 = r1[lane * 2], a1 = r1[lane * 2 + 1];
    float4 b0 = r2[lane * 2], b1 = r2[lane * 2 + 1];
    ushort4* o1 = (ushort4*)(h1 + (size_t)row * D + lane * 8);
    ushort4* o2 = (ushort4*)(h2 + (size_t)row * D + lane * 8);
    o1[0] = make_ushort4(__builtin_bit_cast(u16, (_Float16)a0.x), __builtin_bit_cast(u16, (_Float16)a0.y),
                         __builtin_bit_cast(u16, (_Float16)a0.z), __builtin_bit_cast(u16, (_Float16)a0.w));
    o1[1] = make_ushort4(__builtin_bit_cast(u16, (_Float16)a1.x), __builtin_bit_cast(u16, (_Float16)a1.y),
                         __builtin_bit_cast(u16, (_Float16)a1.z), __builtin_bit_cast(u16, (_Float16)a1.w));
    o2[0] = make_ushort4(__builtin_bit_cast(u16, (_Float16)b0.x), __builtin_bit_cast(u16, (_Float16)b0.y),
                         __builtin_bit_cast(u16, (_Float16)b0.z), __builtin_bit_cast(u16, (_Float16)b0.w));
    o2[1] = make_ushort4(__builtin_bit_cast(u16, (_Float16)b1.x), __builtin_bit_cast(u16, (_Float16)b1.y),
                         __builtin_bit_cast(u16, (_Float16)b1.z), __builtin_bit_cast(u16, (_Float16)b1.w));
    float s1 = 0.f, s2 = 0.f, sr = 0.f;
    float av[8] = {a0.x, a0.y, a0.z, a0.w, a1.x, a1.y, a1.z, a1.w};
    float bv[8] = {b0.x, b0.y, b0.z, b0.w, b1.x, b1.y, b1.z, b1.w};
#pragma unroll
    for (int e = 0; e < 8; ++e) {
        s1 = fmaf(av[e], av[e], s1);
        s2 = fmaf(bv[e], bv[e], s2);
        float d = av[e] - bv[e];
        sr = fmaf(d, d, sr);
    }
#pragma unroll
    for (int off = 32; off > 0; off >>= 1) {
        s1 += __shfl_down(s1, off, 64);
        s2 += __shfl_down(s2, off, 64);
        sr += __shfl_down(sr, off, 64);
    }
    __shared__ float wsr[4];
    if (lane == 0) {
        sq[row] = s1;
        sq[N + row] = s2;
        wsr[wave] = sr;
    }
    __syncthreads();
    if (threadIdx.x == 0)
        accumArr[blockIdx.x] = wsr[0] + wsr[1] + wsr[2] + wsr[3];
}

// ---------------- single-pass f16 MFMA GEMM + dist epilogue + fused round-1 row argmin
// SYMMETRIC triangle compute+store; DOUBLE-BUFFERED K-loop; LDS chunk-XOR swizzle
// (both-sides: pre-swizzled global source + swizzled fragment read, rule #21).
#define BM 128
#define BN 128
#define BK 32
#define NB (N / BM)          // 32 tile rows/cols
#define NPAIR (NB * (NB + 1) / 2)  // 528
#define NT (D / BK)          // 16

__global__ __launch_bounds__(256) void gemm_dist_sym_kernel(const u16* __restrict__ h1,
                                                            const u16* __restrict__ h2,
                                                            const float* __restrict__ sqn,
                                                            float* __restrict__ dist1,
                                                            float* __restrict__ dist2,
                                                            u64* __restrict__ compBest) {
    const int m = blockIdx.z;
    const u16* H = m ? h2 : h1;
    const float* SQ = sqn + (size_t)m * N;
    float* dist = m ? dist2 : dist1;
    u64* cb = compBest + (size_t)m * N;

    // decode linear pair index -> (by, bx), by <= bx
    const int t = blockIdx.x;
    int by = (int)((65.0f - sqrtf(4225.0f - 8.0f * (float)t)) * 0.5f);
    while (by > 0 && by * 32 - by * (by - 1) / 2 > t) --by;
    while ((by + 1) * 32 - (by + 1) * by / 2 <= t) ++by;
    const int bx = by + (t - (by * 32 - by * (by - 1) / 2));
    const bool diag = (by == bx);

    __shared__ u16 SH[4 * BM * BK];          // 32 KB: two (A,B) buffers
    u16* A0 = SH;
    u16* B0 = SH + BM * BK;
    u16* A1 = SH + 2 * BM * BK;
    u16* B1 = SH + 3 * BM * BK;

    const int tid = threadIdx.x;
    const int wave = tid >> 6, lane = tid & 63;
    const int wm = wave >> 1, wn = wave & 1;
    const int row0 = by * BM, col0 = bx * BN;

    floatx4 acc[4][4] = {};

    const int srow = lane >> 2;
    // swizzled source chunk: chunk' = (lane&3) ^ ((srow>>1)&3) = (lane&3) ^ ((lane>>3)&3)
    const int scol = (((lane & 3) ^ ((lane >> 3) & 3))) * 8;

#define STAGE(AB, BB, K0)                                                                      \
    {                                                                                          \
        _Pragma("unroll") for (int i_ = 0; i_ < 2; ++i_) {                                     \
            const int rb_ = wave * 32 + i_ * 16;                                               \
            const u16* ga_ = H + (size_t)(row0 + rb_ + srow) * D + (K0) + scol;                \
            __builtin_amdgcn_global_load_lds(                                                  \
                (const __attribute__((address_space(1))) unsigned int*)ga_,                    \
                (__attribute__((address_space(3))) unsigned int*)&(AB)[rb_ * BK], 16, 0, 0);   \
            if (!diag) {                                                                       \
                const u16* gb_ = H + (size_t)(col0 + rb_ + srow) * D + (K0) + scol;            \
                __builtin_amdgcn_global_load_lds(                                              \
                    (const __attribute__((address_space(1))) unsigned int*)gb_,                \
                    (__attribute__((address_space(3))) unsigned int*)&(BB)[rb_ * BK], 16, 0, 0); \
            }                                                                                  \
        }                                                                                      \
    }

    STAGE(A0, B0, 0);
    __syncthreads();           // buf0 landed

    // swizzled read chunk for fragment row fm = lane&15: cs = (chunk ^ ((fm>>1)&3))*8
    const int cs = (((lane >> 4) ^ ((lane >> 1) & 3))) * 8;
    const int fm = lane & 15;
#pragma unroll 2
    for (int kt = 0; kt < NT; ++kt) {
        u16* Ac = (kt & 1) ? A1 : A0;
        u16* Bc = (kt & 1) ? B1 : B0;
        if (kt + 1 < NT) {
            u16* An = (kt & 1) ? A0 : A1;
            u16* Bn = (kt & 1) ? B0 : B1;
            STAGE(An, Bn, (kt + 1) * BK);
        }
        const u16* Bs = diag ? Ac : Bc;
        f16x8 a8[4], b8[4];
#pragma unroll
        for (int s = 0; s < 4; ++s) {
            a8[s] = *(const f16x8*)&Ac[(wm * 64 + s * 16 + fm) * BK + cs];
            b8[s] = *(const f16x8*)&Bs[(wn * 64 + s * 16 + fm) * BK + cs];
        }
#pragma unroll
        for (int i = 0; i < 4; ++i)
#pragma unroll
            for (int j = 0; j < 4; ++j)
                acc[i][j] = __builtin_amdgcn_mfma_f32_16x16x32_f16(a8[i], b8[j], acc[i][j], 0, 0, 0);
        __syncthreads();       // drains staged loads; protects buffer reuse
    }
#undef STAGE

    float* Cs = (float*)SH + wave * 1024;

    const int lr = lane & 15;
    const int lq = lane >> 4;
    float sc[4];
#pragma unroll
    for (int ns = 0; ns < 4; ++ns) sc[ns] = SQ[col0 + wn * 64 + ns * 16 + lr];
    u64 colBest[4] = {~0ull, ~0ull, ~0ull, ~0ull};
#pragma unroll
    for (int ms = 0; ms < 4; ++ms) {
        const int rb = row0 + wm * 64 + ms * 16 + lq * 4;
        float srow_[4];
#pragma unroll
        for (int r = 0; r < 4; ++r) srow_[r] = SQ[rb + r];
#pragma unroll
        for (int r = 0; r < 4; ++r) {
            const int row = rb + r;
            float dval[4];
#pragma unroll
            for (int ns = 0; ns < 4; ++ns) {
                const int col = col0 + wn * 64 + ns * 16 + lr;
                float d2 = srow_[r] + sc[ns] - 2.0f * acc[ms][ns][r];
                dval[ns] = (row == col) ? BIG : sqrtf(fmaxf(d2, 1e-12f));
            }
            float vmin = fminf(fminf(dval[0], dval[1]), fminf(dval[2], dval[3]));
            int nsel = (dval[0] == vmin) ? 0 : (dval[1] == vmin) ? 1 : (dval[2] == vmin) ? 2 : 3;
            u64 pmin = (((u64)__float_as_uint(vmin)) << 32) | (unsigned)(col0 + wn * 64 + nsel * 16 + lr);
#pragma unroll
            for (int msk = 1; msk < 16; msk <<= 1) {
                u64 o = __shfl_xor(pmin, msk, 64);
                pmin = o < pmin ? o : pmin;
            }
            if (lr == 0) atomicMin(&cb[row], pmin);
            if (!diag) {
#pragma unroll
                for (int ns = 0; ns < 4; ++ns) {
                    u64 p = (((u64)__float_as_uint(dval[ns])) << 32) | (unsigned)row;
                    colBest[ns] = p < colBest[ns] ? p : colBest[ns];
                }
            }
#pragma unroll
            for (int ns = 0; ns < 4; ++ns)
                Cs[(lq * 4 + r) * 64 + ns * 16 + lr] = dval[ns];
        }
        // triangle tile store only (rows of dist)
#pragma unroll
        for (int p = 0; p < 4; ++p) {
            float4 v4 = *(float4*)&Cs[p * 256 + lane * 4];
            const int gr = row0 + wm * 64 + ms * 16 + p * 4 + (lane >> 4);
            const int gc = col0 + wn * 64 + (lane & 15) * 4;
            *(float4*)&dist[(size_t)gr * N + gc] = v4;
        }
    }
    // column argmin -> compBest for the mirror rows (off-diagonal only)
    if (!diag) {
#pragma unroll
        for (int ns = 0; ns < 4; ++ns) {
            u64 b = colBest[ns];
            u64 o = __shfl_xor(b, 16, 64);
            b = o < b ? o : b;
            o = __shfl_xor(b, 32, 64);
            b = o < b ? o : b;
            if (lq == 0) atomicMin(&cb[col0 + wn * 64 + ns * 16 + lr], b);
        }
    }
}

// ---------------- merge round 1 (blocks 0,1) + distc +inf init (blocks 2..1025)
__global__ __launch_bounds__(1024) void merge1i_kernel(int* __restrict__ comp,
                                                       u64* __restrict__ compBest,
                                                       float* __restrict__ deaths,
                                                       int* __restrict__ cnt,
                                                       int* __restrict__ numComp,
                                                       int* __restrict__ numC1,
                                                       unsigned* __restrict__ distc_u) {
    const int t = threadIdx.x;
    if (blockIdx.x >= 2) {
        const size_t idx = (size_t)(blockIdx.x - 2) * 1024 + t;
        uint4 v = make_uint4(0x7f800000u, 0x7f800000u, 0x7f800000u, 0x7f800000u);
        ((uint4*)distc_u)[idx] = v;
        ((uint4*)distc_u)[idx + 1048576] = v;
        return;
    }
    const int m = blockIdx.x;
    int* cp = comp + (size_t)m * N;
    u64* cb = compBest + (size_t)m * N;
    float* dth = deaths + (size_t)m * N;

    __shared__ int pa[N];
    __shared__ int pb[N];
    __shared__ unsigned flagbits[NW];
    __shared__ int wpc[NW];
    __shared__ int done;

    if (t == 0) cnt[m] = 0;
    __syncthreads();

    for (int c = t; c < N; c += 1024) {
        u64 best = cb[c];
        int p = c;
        if (best != ~0ull) {
            int j = (int)(unsigned)best;
            int c2 = cp[j];
            u64 best2 = cb[c2];
            int j2 = (int)(unsigned)best2;
            bool mutual = (cp[j2] == c);
            if (!(mutual && c < c2)) {
                p = c2;
                int idx = atomicAdd(cnt + m, 1);
                dth[idx] = __uint_as_float((unsigned)(best >> 32));
            }
        }
        pa[c] = p;
    }

    int* A = pa;
    int* B = pb;
    while (true) {
        __syncthreads();
        if (t == 0) done = 1;
        __syncthreads();
        bool ch = false;
        for (int c = t; c < N; c += 1024) {
            int g = A[A[c]];
            B[c] = g;
            ch |= (g != A[c]);
        }
        if (ch) done = 0;
        __syncthreads();
        int* tmp = A; A = B; B = tmp;
        if (done) break;
    }

    for (int w = t; w < NW; w += 1024) flagbits[w] = 0u;
    __syncthreads();
    for (int i = t; i < N; i += 1024)
        atomicOr(&flagbits[A[i] >> 5], 1u << (A[i] & 31));
    __syncthreads();
    if (t < NW) wpc[t] = __popc(flagbits[t]);
    __syncthreads();
    for (int off = 1; off < NW; off <<= 1) {
        int v = 0;
        if (t < NW) v = wpc[t] + ((t >= off) ? wpc[t - off] : 0);
        __syncthreads();
        if (t < NW) wpc[t] = v;
        __syncthreads();
    }
    for (int i = t; i < N; i += 1024) {
        int root = A[i];
        int w = root >> 5, b = root & 31;
        int base = w ? wpc[w - 1] : 0;
        unsigned mask = b ? ((1u << b) - 1u) : 0u;
        cp[i] = base + __popc(flagbits[w] & mask);
    }
    for (int c = t; c < N; c += 1024) cb[c] = ~0ull;
    if (t == 0) {
        int C1 = wpc[NW - 1];
        numC1[m] = C1;
        numComp[m] = C1;
    }
}

// ---------------- atomic level-1 contraction, TRIANGLE reads only.
// One block per row (full parallelism — R5 lesson: never serialize rows per block).
// LDS bins restricted to ceil64(C1); flush via global atomicMin.
__global__ __launch_bounds__(256) void rowatomic_kernel(const float* __restrict__ dist1,
                                                        const float* __restrict__ dist2,
                                                        const int* __restrict__ comp,
                                                        const int* __restrict__ numC1,
                                                        unsigned* __restrict__ distc_u) {
    const int m = blockIdx.y;
    const int cend = (numC1[m] + 63) & ~63;
    const float* dist = m ? dist2 : dist1;
    const int* cp = comp + (size_t)m * N;
    const int i = blockIdx.x;
    const float4* row4 = (const float4*)(dist + (size_t)i * N);
    const int4* cp4 = (const int4*)cp;
    __shared__ unsigned bins[CMAX];
    const int t = threadIdx.x;
    for (int b = t; b < cend; b += 256) bins[b] = 0x7f800000u;
    __syncthreads();
    const int q0 = (i >> 7) << 5;   // float4 index of this row's diagonal-tile start
    for (int q = q0 + t; q < N / 4; q += 256) {
        float4 v = row4[q];
        int4 cj = cp4[q];
        atomicMin(&bins[cj.x], __float_as_uint(v.x));
        atomicMin(&bins[cj.y], __float_as_uint(v.y));
        atomicMin(&bins[cj.z], __float_as_uint(v.z));
        atomicMin(&bins[cj.w], __float_as_uint(v.w));
    }
    __syncthreads();
    unsigned* drow = distc_u + ((size_t)m * CMAX + cp[i]) * CMAX;
    for (int b = t; b < cend; b += 256) {
        unsigned v = bins[b];
        if (v != 0x7f800000u) atomicMin(&drow[b], v);
    }
}

// ---------------- FUSED symmetrize + round-2 scan + distc2 init
#define CT 64
#define NCT (CMAX / CT)                // 32
#define NPAIRC (NCT * (NCT + 1) / 2)   // 528
__global__ __launch_bounds__(256) void symscan_kernel(unsigned* __restrict__ distc_u,
                                                      u64* __restrict__ compBest,
                                                      const int* __restrict__ numComp,
                                                      const int* __restrict__ numC1,
                                                      unsigned* __restrict__ distc2_u) {
    const int tid = threadIdx.x;
    if (blockIdx.x >= NPAIRC) {
        // init distc2: 2*CMAX2*CMAX2 floats = 524,288 uint4; (256 blocks x 2 y) x 256 thr x 4
        const size_t base = ((size_t)blockIdx.y * 256 + (blockIdx.x - NPAIRC)) * 256 + tid;
        uint4 v = make_uint4(0x7f800000u, 0x7f800000u, 0x7f800000u, 0x7f800000u);
#pragma unroll
        for (int k = 0; k < 4; ++k)
            ((uint4*)distc2_u)[base + (size_t)k * 131072] = v;
        return;
    }
    const int m = blockIdx.y;
    if (numComp[m] <= 1) return;
    const int C1 = numC1[m];
    const int t = blockIdx.x;
    int a = (int)((65.0f - sqrtf(4225.0f - 8.0f * (float)t)) * 0.5f);
    while (a > 0 && a * 32 - a * (a - 1) / 2 > t) --a;
    while ((a + 1) * 32 - (a + 1) * a / 2 <= t) ++a;
    const int b = a + (t - (a * 32 - a * (a - 1) / 2));
    if (a * CT >= C1 || b * CT >= C1) return;   // all-inf region, never read downstream

    unsigned* Dm = distc_u + (size_t)m * CMAX * CMAX;
    unsigned* P = Dm + (size_t)(a * CT) * CMAX + b * CT;   // tile (a,b)
    unsigned* Q = Dm + (size_t)(b * CT) * CMAX + a * CT;   // tile (b,a)
    u64* cb = compBest + (size_t)m * N;

    __shared__ float L[CT][CT + 1];
    __shared__ float M[CT][CT + 1];
#pragma unroll
    for (int e0 = 0; e0 < 4; ++e0) {
        int e = e0 * 256 + tid;
        int r = e >> 4, c4 = (e & 15) << 2;
        float4 v = *(const float4*)&Q[(size_t)r * CMAX + c4];
        L[r][c4] = v.x; L[r][c4 + 1] = v.y; L[r][c4 + 2] = v.z; L[r][c4 + 3] = v.w;
    }
    __syncthreads();
#pragma unroll
    for (int e0 = 0; e0 < 4; ++e0) {
        int e = e0 * 256 + tid;
        int r = e >> 4, c4 = (e & 15) << 2;
        float4 v = *(const float4*)&P[(size_t)r * CMAX + c4];
        float4 f;
        f.x = fminf(v.x, L[c4 + 0][r]);
        f.y = fminf(v.y, L[c4 + 1][r]);
        f.z = fminf(v.z, L[c4 + 2][r]);
        f.w = fminf(v.w, L[c4 + 3][r]);
        *(float4*)&P[(size_t)r * CMAX + c4] = f;
        M[r][c4] = f.x; M[r][c4 + 1] = f.y; M[r][c4 + 2] = f.z; M[r][c4 + 3] = f.w;
    }
    __syncthreads();

    // direction 1: rows of tile a over cols of tile b (S rows)
    {
        const int rloc = tid >> 2;
        const int r = a * CT + rloc;
        const int c0 = (tid & 3) * 16;
        u64 best = ~0ull;
#pragma unroll
        for (int c = 0; c < 16; ++c) {
            const int j = b * CT + c0 + c;
            const unsigned bits = __float_as_uint(M[rloc][c0 + c]);
            if (j < C1 && j != r && bits < 0x7f800000u) {
                u64 p = (((u64)bits) << 32) | (unsigned)j;
                best = p < best ? p : best;
            }
        }
        u64 o = __shfl_xor(best, 1, 64); best = o < best ? o : best;
        o = __shfl_xor(best, 2, 64); best = o < best ? o : best;
        if ((tid & 3) == 0 && r < C1 && best != ~0ull) atomicMin(&cb[r], best);
    }

    if (a == b) return;

    // direction 2: rows of tile b over cols of tile a (S^T = M columns)
    {
        const int rloc = tid >> 2;
        const int r = b * CT + rloc;
        const int c0 = (tid & 3) * 16;
        u64 best = ~0ull;
#pragma unroll
        for (int c = 0; c < 16; ++c) {
            const int j = a * CT + c0 + c;
            const unsigned bits = __float_as_uint(M[c0 + c][rloc]);
            if (j < C1 && bits < 0x7f800000u) {   // j != r guaranteed (a != b)
                u64 p = (((u64)bits) << 32) | (unsigned)j;
                best = p < best ? p : best;
            }
        }
        u64 o = __shfl_xor(best, 1, 64); best = o < best ? o : best;
        o = __shfl_xor(best, 2, 64); best = o < best ? o : best;
        if ((tid & 3) == 0 && r < C1 && best != ~0ull) atomicMin(&cb[r], best);
    }

    // write back S^T to tile (b,a)
#pragma unroll
    for (int e0 = 0; e0 < 4; ++e0) {
        int e = e0 * 256 + tid;
        int r = e >> 4, c4 = (e & 15) << 2;
        float4 f;
        f.x = M[c4 + 0][r];
        f.y = M[c4 + 1][r];
        f.z = M[c4 + 2][r];
        f.w = M[c4 + 3][r];
        *(float4*)&Q[(size_t)r * CMAX + c4] = f;
    }
}

// ---------------- merge round 2 (trimmed): hook + jump + dense relabel + comp_c2 identity
__global__ __launch_bounds__(1024) void merge2_kernel(int* __restrict__ comp_c,
                                                      u64* __restrict__ compBest,
                                                      float* __restrict__ deaths,
                                                      int* __restrict__ cnt,
                                                      int* __restrict__ numComp,
                                                      const int* __restrict__ numC1,
                                                      int* __restrict__ numC2,
                                                      int* __restrict__ comp_c2) {
    const int m = blockIdx.x;
    const int t = threadIdx.x;
    const int C1 = numC1[m];
    int* cc2i = comp_c2 + (size_t)m * CMAX2;
    for (int c = t; c < CMAX2; c += 1024) cc2i[c] = c;
    if (numComp[m] <= 1) {
        if (t == 0) numC2[m] = numComp[m];
        return;
    }
    int* cc = comp_c + (size_t)m * CMAX;
    u64* cb = compBest + (size_t)m * N;
    float* dth = deaths + (size_t)m * N;

    __shared__ int pa[CMAX];
    __shared__ int pb[CMAX];
    __shared__ unsigned flagbits[CMAX / 32];
    __shared__ int wpc[CMAX / 32];
    __shared__ int done;

    for (int c = t; c < C1; c += 1024) {
        u64 best = cb[c];
        int p = c;
        if (best != ~0ull) {
            int j = (int)(unsigned)best;
            int c2 = cc[j];
            u64 best2 = cb[c2];
            int j2 = (int)(unsigned)best2;
            bool mutual = (cc[j2] == c);
            if (!(mutual && c < c2)) {
                p = c2;
                int idx = atomicAdd(cnt + m, 1);
                dth[idx] = __uint_as_float((unsigned)(best >> 32));
            }
        }
        pa[c] = p;
    }

    int* A = pa;
    int* B = pb;
    while (true) {
        __syncthreads();
        if (t == 0) done = 1;
        __syncthreads();
        bool ch = false;
        for (int c = t; c < C1; c += 1024) {
            int g = A[A[c]];
            B[c] = g;
            ch |= (g != A[c]);
        }
        if (ch) done = 0;
        __syncthreads();
        int* tmp = A; A = B; B = tmp;
        if (done) break;
    }

    for (int w = t; w < CMAX / 32; w += 1024) flagbits[w] = 0u;
    __syncthreads();
    for (int j = t; j < C1; j += 1024)
        atomicOr(&flagbits[A[j] >> 5], 1u << (A[j] & 31));
    __syncthreads();
    if (t < CMAX / 32) wpc[t] = __popc(flagbits[t]);
    __syncthreads();
    for (int off = 1; off < CMAX / 32; off <<= 1) {
        int v = 0;
        if (t < CMAX / 32) v = wpc[t] + ((t >= off) ? wpc[t - off] : 0);
        __syncthreads();
        if (t < CMAX / 32) wpc[t] = v;
        __syncthreads();
    }
    for (int j = t; j < C1; j += 1024) {
        int root = A[j];
        int w = root >> 5, b = root & 31;
        int base = w ? wpc[w - 1] : 0;
        unsigned mask = b ? ((1u << b) - 1u) : 0u;
        cc[j] = base + __popc(flagbits[w] & mask);
    }
    for (int c = t; c < C1; c += 1024) cb[c] = ~0ull;
    if (t == 0) {
        int C2 = wpc[CMAX / 32 - 1];
        numC2[m] = C2;
        numComp[m] = C2;
    }
}

// ---------------- atomic level-2 contraction: row of distc -> bins[C2] -> distc2
__global__ __launch_bounds__(256) void rowatomic2_kernel(const float* __restrict__ distc,
                                                         const int* __restrict__ comp_c,
                                                         const int* __restrict__ numComp,
                                                         const int* __restrict__ numC1,
                                                         unsigned* __restrict__ distc2_u) {
    const int m = blockIdx.y;
    if (numComp[m] <= 1) return;
    const int C1 = numC1[m];
    const int r = blockIdx.x;
    if (r >= C1) return;
    const int* cc = comp_c + (size_t)m * CMAX;
    const float* row = distc + ((size_t)m * CMAX + r) * CMAX;
    __shared__ unsigned bins[CMAX2];
    const int t = threadIdx.x;
    for (int b = t; b < CMAX2; b += 256) bins[b] = 0x7f800000u;
    __syncthreads();
    for (int j = t; j < C1; j += 256)
        atomicMin(&bins[cc[j]], __float_as_uint(row[j]));
    __syncthreads();
    unsigned* drow = distc2_u + ((size_t)m * CMAX2 + cc[r]) * CMAX2;
    for (int b = t; b < CMAX2; b += 256) {
        unsigned v = bins[b];
        if (v != 0x7f800000u) atomicMin(&drow[b], v);
    }
}

// ---------------- level-3 scan over distc2 (blocks < 2*CMAX2) + distc3 +inf init (rest)
__global__ __launch_bounds__(256) void scan3_kernel(const float* __restrict__ distc2,
                                                    const int* __restrict__ comp_c2,
                                                    u64* __restrict__ compBest,
                                                    const int* __restrict__ numComp,
                                                    const int* __restrict__ numC2,
                                                    unsigned* __restrict__ distc3_u) {
    const int t = threadIdx.x;
    if (blockIdx.x >= 2 * CMAX2) {
        // init distc3: 2*512*512 floats = 131072 uint4; 256 blocks x 256 thr x 2
        const size_t idx = (size_t)(blockIdx.x - 2 * CMAX2) * 256 + t;
        uint4 v = make_uint4(0x7f800000u, 0x7f800000u, 0x7f800000u, 0x7f800000u);
        ((uint4*)distc3_u)[idx] = v;
        ((uint4*)distc3_u)[idx + 65536] = v;
        return;
    }
    const int m = blockIdx.x >> 10;          // CMAX2 = 1024
    if (numComp[m] <= 1) return;
    const int C2 = numC2[m];
    const int r = blockIdx.x & (CMAX2 - 1);
    if (r >= C2) return;
    const int* cc = comp_c2 + (size_t)m * CMAX2;
    u64* cb = compBest + (size_t)m * N;
    const int myc = cc[r];
    const float4* row4 = (const float4*)(distc2 + ((size_t)m * CMAX2 + r) * CMAX2);
    const int4* cc4 = (const int4*)cc;
    float4 v = row4[t];
    int4 cj = cc4[t];
    int j0 = t * 4;
    u64 p0 = (j0 + 0 < C2 && cj.x != myc) ? ((((u64)__float_as_uint(v.x)) << 32) | (unsigned)(j0 + 0)) : ~0ull;
    u64 p1 = (j0 + 1 < C2 && cj.y != myc) ? ((((u64)__float_as_uint(v.y)) << 32) | (unsigned)(j0 + 1)) : ~0ull;
    u64 p2 = (j0 + 2 < C2 && cj.z != myc) ? ((((u64)__float_as_uint(v.z)) << 32) | (unsigned)(j0 + 2)) : ~0ull;
    u64 p3 = (j0 + 3 < C2 && cj.w != myc) ? ((((u64)__float_as_uint(v.w)) << 32) | (unsigned)(j0 + 3)) : ~0ull;
    u64 q0 = p0 < p1 ? p0 : p1;
    u64 q1 = p2 < p3 ? p2 : p3;
    u64 best = q0 < q1 ? q0 : q1;
#pragma unroll
    for (int off = 32; off > 0; off >>= 1) {
        u64 o = __shfl_down(best, off, 64);
        best = o < best ? o : best;
    }
    if ((t & 63) == 0) atomicMin(cb + myc, best);
}

// ---------------- merge round 3: hook + jump + dense relabel of comp_c2
__global__ __launch_bounds__(1024) void merge3_kernel(int* __restrict__ comp_c2,
                                                      u64* __restrict__ compBest,
                                                      float* __restrict__ deaths,
                                                      int* __restrict__ cnt,
                                                      int* __restrict__ numComp,
                                                      const int* __restrict__ numC2,
                                                      int* __restrict__ numC3) {
    const int m = blockIdx.x;
    const int t = threadIdx.x;
    if (numComp[m] <= 1) {
        if (t == 0) numC3[m] = numComp[m];
        return;
    }
    const int C2 = numC2[m];
    int* cc = comp_c2 + (size_t)m * CMAX2;
    u64* cb = compBest + (size_t)m * N;
    float* dth = deaths + (size_t)m * N;

    __shared__ int pa[CMAX2];
    __shared__ int pb[CMAX2];
    __shared__ unsigned flagbits[CMAX2 / 32];
    __shared__ int wpc[CMAX2 / 32];
    __shared__ int done;

    for (int c = t; c < C2; c += 1024) {
        u64 best = cb[c];
        int p = c;
        if (best != ~0ull) {
            int j = (int)(unsigned)best;
            int c2 = cc[j];
            u64 best2 = cb[c2];
            int j2 = (int)(unsigned)best2;
            bool mutual = (cc[j2] == c);
            if (!(mutual && c < c2)) {
                p = c2;
                int idx = atomicAdd(cnt + m, 1);
                dth[idx] = __uint_as_float((unsigned)(best >> 32));
            }
        }
        pa[c] = p;
    }

    int* A = pa;
    int* B = pb;
    while (true) {
        __syncthreads();
        if (t == 0) done = 1;
        __syncthreads();
        bool ch = false;
        for (int c = t; c < C2; c += 1024) {
            int g = A[A[c]];
            B[c] = g;
            ch |= (g != A[c]);
        }
        if (ch) done = 0;
        __syncthreads();
        int* tmp = A; A = B; B = tmp;
        if (done) break;
    }

    for (int w = t; w < CMAX2 / 32; w += 1024) flagbits[w] = 0u;
    __syncthreads();
    for (int j = t; j < C2; j += 1024)
        atomicOr(&flagbits[A[j] >> 5], 1u << (A[j] & 31));
    __syncthreads();
    if (t < CMAX2 / 32) wpc[t] = __popc(flagbits[t]);
    __syncthreads();
    for (int off = 1; off < CMAX2 / 32; off <<= 1) {
        int v = 0;
        if (t < CMAX2 / 32) v = wpc[t] + ((t >= off) ? wpc[t - off] : 0);
        __syncthreads();
        if (t < CMAX2 / 32) wpc[t] = v;
        __syncthreads();
    }
    for (int j = t; j < C2; j += 1024) {
        int root = A[j];
        int w = root >> 5, b = root & 31;
        int base = w ? wpc[w - 1] : 0;
        unsigned mask = b ? ((1u << b) - 1u) : 0u;
        cc[j] = base + __popc(flagbits[w] & mask);
    }
    for (int c = t; c < C2; c += 1024) cb[c] = ~0ull;
    if (t == 0) {
        int C3 = wpc[CMAX2 / 32 - 1];
        numC3[m] = C3;
        numComp[m] = C3;
    }
}

// ---------------- atomic level-3 contraction: row of distc2 -> bins[C3] -> distc3
__global__ __launch_bounds__(256) void rowatomic3_kernel(const float* __restrict__ distc2,
                                                         const int* __restrict__ comp_c2,
                                                         const int* __restrict__ numComp,
                                                         const int* __restrict__ numC2,
                                                         unsigned* __restrict__ distc3_u) {
    const int m = blockIdx.y;
    if (numComp[m] <= 1) return;
    const int C2 = numC2[m];
    const int r = blockIdx.x;
    if (r >= C2) return;
    const int* cc = comp_c2 + (size_t)m * CMAX2;
    const float* row = distc2 + ((size_t)m * CMAX2 + r) * CMAX2;
    __shared__ unsigned bins[CMAX3];
    const int t = threadIdx.x;
    for (int b = t; b < CMAX3; b += 256) bins[b] = 0x7f800000u;
    __syncthreads();
    for (int j = t; j < C2; j += 256)
        atomicMin(&bins[cc[j]], __float_as_uint(row[j]));
    __syncthreads();
    unsigned* drow = distc3_u + ((size_t)m * CMAX3 + cc[r]) * CMAX3;
    for (int b = t; b < CMAX3; b += 256) {
        unsigned v = bins[b];
        if (v != 0x7f800000u) atomicMin(&drow[b], v);
    }
}

// ---------------- finish: rounds >= 4 on distc3 + register-bitonic sort + fused final
__global__ __launch_bounds__(1024) void finish_kernel(const float* __restrict__ distc3,
                                                      float* __restrict__ deaths,
                                                      int* __restrict__ cnt,
                                                      int* __restrict__ numComp,
                                                      const int* __restrict__ numC3,
                                                      const float* __restrict__ accumArr,
                                                      int* __restrict__ doneFlag,
                                                      float* __restrict__ out) {
    const int m = blockIdx.x;
    int nc = numComp[m];
    const int C3 = numC3[m];
    const float* Dm = distc3 + (size_t)m * CMAX3 * CMAX3;
    float* dth = deaths + (size_t)m * N;
    const int t = threadIdx.x;
    const int wave = t >> 6, lane = t & 63;
    __shared__ int comp[CMAX3];
    __shared__ u64 cb[CMAX3];
    __shared__ int pa[CMAX3];
    __shared__ int pb[CMAX3];
    __shared__ unsigned flags[CMAX3 / 32];
    __shared__ int done, ncs, lastf;
    __shared__ float s[N];
    __shared__ float wsum[16];
    __shared__ float rsum[16];

    if (nc > 1) {
        for (int c = t; c < C3; c += 1024) {
            comp[c] = c;
            cb[c] = ~0ull;
        }
        __syncthreads();

        for (int round = 0; round < 10 && nc > 1; ++round) {
            for (int r = wave; r < C3; r += 16) {
                const int myc = comp[r];
                const float* row = Dm + (size_t)r * CMAX3;
                u64 best = ~0ull;
                for (int j = lane; j < C3; j += 64) {
                    if (comp[j] != myc) {
                        u64 p = (((u64)__float_as_uint(row[j])) << 32) | (unsigned)j;
                        best = p < best ? p : best;
                    }
                }
#pragma unroll
                for (int off = 32; off > 0; off >>= 1) {
                    u64 o = __shfl_down(best, off, 64);
                    best = o < best ? o : best;
                }
                if (lane == 0) atomicMin(&cb[myc], best);
            }
            __syncthreads();
            for (int c = t; c < C3; c += 1024) {
                u64 best = cb[c];
                int p = c;
                if (best != ~0ull) {
                    int j = (int)(unsigned)best;
                    int c2 = comp[j];
                    u64 best2 = cb[c2];
                    int j2 = (int)(unsigned)best2;
                    bool mutual = (comp[j2] == c);
                    if (!(mutual && c < c2)) {
                        p = c2;
                        int idx = atomicAdd(cnt + m, 1);
                        dth[idx] = __uint_as_float((unsigned)(best >> 32));
                    }
                }
                pa[c] = p;
            }
            int* A = pa; int* B = pb;
            while (true) {
                __syncthreads();
                if (t == 0) done = 1;
                __syncthreads();
                bool ch = false;
                for (int c = t; c < C3; c += 1024) {
                    int g = A[A[c]];
                    B[c] = g;
                    ch |= (g != A[c]);
                }
                if (ch) done = 0;
                __syncthreads();
                int* tmp = A; A = B; B = tmp;
                if (done) break;
            }
            for (int w = t; w < CMAX3 / 32; w += 1024) flags[w] = 0u;
            __syncthreads();
            for (int j = t; j < C3; j += 1024) {
                int root = A[comp[j]];
                comp[j] = root;
                atomicOr(&flags[root >> 5], 1u << (root & 31));
            }
            for (int c = t; c < C3; c += 1024) cb[c] = ~0ull;
            __syncthreads();
            if (t == 0) {
                int sacc = 0;
                for (int w = 0; w < CMAX3 / 32; ++w) sacc += __popc(flags[w]);
                ncs = sacc;
            }
            __syncthreads();
            nc = ncs;
        }
        if (t == 0) numComp[m] = nc;
    }
    __syncthreads();

    // ---- register-resident bitonic sort (ascending) of the 4096 deaths.
    const int t4 = t << 2;
    float v0, v1, v2, v3;
    {
        float4 l4 = *(const float4*)&dth[t4];
        v0 = l4.x; v1 = l4.y; v2 = l4.z; v3 = l4.w;
        if (t == 1023) v3 = BIG;   // element N-1 pad
    }
#define CSWAP(a, b, up)                         \
    {                                           \
        float mn_ = fminf(a, b), mx_ = fmaxf(a, b); \
        a = (up) ? mn_ : mx_;                   \
        b = (up) ? mx_ : mn_;                   \
    }
    for (int k = 2; k <= N; k <<= 1) {
        for (int jj = k >> 1; jj > 0; jj >>= 1) {
            if (jj >= 256) {
                s[t4] = v0; s[t4 + 1] = v1; s[t4 + 2] = v2; s[t4 + 3] = v3;
                __syncthreads();
                const bool up = ((t4 & k) == 0);
                const bool lower = ((t4 & jj) == 0);
                const bool mk = (up == lower);
                float o0 = s[t4 ^ jj], o1 = s[(t4 + 1) ^ jj];
                float o2 = s[(t4 + 2) ^ jj], o3 = s[(t4 + 3) ^ jj];
                v0 = mk ? fminf(v0, o0) : fmaxf(v0, o0);
                v1 = mk ? fminf(v1, o1) : fmaxf(v1, o1);
                v2 = mk ? fminf(v2, o2) : fmaxf(v2, o2);
                v3 = mk ? fminf(v3, o3) : fmaxf(v3, o3);
                __syncthreads();
            } else if (jj >= 4) {
                const int sl = jj >> 2;
                const bool up = ((t4 & k) == 0);
                const bool lower = ((lane & sl) == 0);
                const bool mk = (up == lower);
                float o0 = __shfl_xor(v0, sl, 64);
                float o1 = __shfl_xor(v1, sl, 64);
                float o2 = __shfl_xor(v2, sl, 64);
                float o3 = __shfl_xor(v3, sl, 64);
                v0 = mk ? fminf(v0, o0) : fmaxf(v0, o0);
                v1 = mk ? fminf(v1, o1) : fmaxf(v1, o1);
                v2 = mk ? fminf(v2, o2) : fmaxf(v2, o2);
                v3 = mk ? fminf(v3, o3) : fmaxf(v3, o3);
            } else if (jj == 2) {
                const bool up = ((t4 & k) == 0);
                CSWAP(v0, v2, up);
                CSWAP(v1, v3, up);
            } else {
                const bool u01 = ((t4 & k) == 0);
                const bool u23 = (((t4 + 2) & k) == 0);
                CSWAP(v0, v1, u01);
                CSWAP(v2, v3, u23);
            }
        }
    }
#undef CSWAP
    *(float4*)&dth[t4] = make_float4(v0, v1, v2, v3);

    // last-block fused final (device-scope ticket; grid-order independent)
    __threadfence();
    __syncthreads();
    if (t == 0) lastf = (atomicAdd(doneFlag, 1) == 1) ? 1 : 0;
    __syncthreads();
    if (!lastf) return;
    __threadfence();
    const float* s1 = deaths;
    const float* s2 = deaths + N;
    float sum = 0.f;
    for (int i = t; i < N - 1; i += 1024) {
        float a = s1[i], b = s2[i];
        sum += fminf(fabsf(a - b), 0.5f * (a + b));
    }
    float ra = accumArr[t];
#pragma unroll
    for (int off = 32; off > 0; off >>= 1) {
        sum += __shfl_down(sum, off, 64);
        ra += __shfl_down(ra, off, 64);
    }
    if (lane == 0) { wsum[wave] = sum; rsum[wave] = ra; }
    __syncthreads();
    if (t == 0) {
        float tot = 0.f, rt = 0.f;
        for (int k = 0; k < 16; ++k) { tot += wsum[k]; rt += rsum[k]; }
        out[0] = rt * (1.0f / ((float)N * (float)D)) + tot;
    }
}

extern "C" void kernel_launch(void* const* d_in, const int* in_sizes, int n_in,
                              void* d_out, int out_size, void* d_ws, size_t ws_size,
                              hipStream_t stream) {
    const float* x1 = (const float*)d_in[0];
    const float* x2 = (const float*)d_in[1];
    float* out = (float*)d_out;
    float* ws = (float*)d_ws;

    const size_t nn = (size_t)N * N;
    const size_t cc2 = (size_t)CMAX * CMAX;

    float* dist1 = ws;
    float* dist2 = ws + nn;
    float* distc = ws + 2 * nn;
    u16* h1 = (u16*)distc;                 // alias: dead before merge1i's init overwrites
    u16* h2 = h1 + (size_t)N * D;
    u64* compBest = (u64*)(distc + 2 * cc2);
    int* comp      = (int*)(compBest + 2 * N);
    int* comp_c    = comp + 2 * N;
    float* deaths  = (float*)(comp_c + 2 * CMAX);
    int* cnt       = (int*)(deaths + 2 * N);
    int* numComp   = cnt + 2;
    int* numC1     = numComp + 2;
    int* numC2     = numC1 + 2;
    int* numC3     = numC2 + 2;
    int* doneFlag  = numC3 + 2;
    float* sq      = (float*)(doneFlag + 2);
    float* accumArr = sq + 2 * N;          // 1024 floats
    // level-2 buffers alias dist1 (dead after rowatomic) — distc2 init'd in symscan's
    // extra blocks, comp_c2 in merge2. Level-3 distc3 aliases distc (dead after
    // rowatomic2), init'd in scan3's extra blocks. NEVER earlier.
    float* distc2  = dist1;
    int* comp_c2   = (int*)(distc2 + 2 * (size_t)CMAX2 * CMAX2);
    float* distc3  = distc;

    prep_kernel<<<N / 4, 256, 0, stream>>>(x1, x2, h1, h2, sq, accumArr, comp, compBest,
                                           comp_c, doneFlag);
    gemm_dist_sym_kernel<<<dim3(NPAIR, 1, 2), 256, 0, stream>>>(h1, h2, sq, dist1, dist2, compBest);
    merge1i_kernel<<<2 + 1024, 1024, 0, stream>>>(comp, compBest, deaths, cnt, numComp, numC1,
                                                  (unsigned*)distc);
    rowatomic_kernel<<<dim3(N, 2), 256, 0, stream>>>(dist1, dist2, comp, numC1, (unsigned*)distc);
    symscan_kernel<<<dim3(NPAIRC + 256, 2), 256, 0, stream>>>((unsigned*)distc, compBest,
                                                              numComp, numC1, (unsigned*)distc2);
    merge2_kernel<<<2, 1024, 0, stream>>>(comp_c, compBest, deaths, cnt, numComp, numC1, numC2,
                                          comp_c2);
    rowatomic2_kernel<<<dim3(CMAX, 2), 256, 0, stream>>>(distc, comp_c, numComp, numC1,
                                                         (unsigned*)distc2);
    scan3_kernel<<<2 * CMAX2 + 256, 256, 0, stream>>>(distc2, comp_c2, compBest, numComp, numC2,
                                                      (unsigned*)distc3);
    merge3_kernel<<<2, 1024, 0, stream>>>(comp_c2, compBest, deaths, cnt, numComp, numC2, numC3);
    rowatomic3_kernel<<<dim3(CMAX2, 2), 256, 0, stream>>>(distc2, comp_c2, numComp, numC2,
                                                          (unsigned*)distc3);
    finish_kernel<<<2, 1024, 0, stream>>>(distc3, deaths, cnt, numComp, numC3,
                                          accumArr, doneFlag, out);
}

// Round 7
// 215.980 us; speedup vs baseline: 2.5216x; 1.0527x over previous
//
#include <hip/hip_runtime.h>

#define N 4096
#define D 512
#define BIG 1e30f
#define CMAX 2048
#define CMAX2 1024
#define CMAX3 512
#define NW (N / 32)

typedef unsigned long long u64;
typedef unsigned short u16;
typedef _Float16 f16x8 __attribute__((ext_vector_type(8)));
typedef float floatx4 __attribute__((ext_vector_type(4)));

// ---------------- fused prep: f32->f16 convert + row sq-norms + repr partial + init
__global__ __launch_bounds__(256) void prep_kernel(const float* __restrict__ x1,
                                                   const float* __restrict__ x2,
                                                   u16* __restrict__ h1,
                                                   u16* __restrict__ h2,
                                                   float* __restrict__ sq,
                                                   float* __restrict__ accumArr,
                                                   int* __restrict__ comp,
                                                   u64* __restrict__ compBest,
                                                   int* __restrict__ comp_c,
                                                   int* __restrict__ doneFlag) {
    const int tid = blockIdx.x * 256 + threadIdx.x;
    if (tid < 2 * N) {
        comp[tid] = tid & (N - 1);
        compBest[tid] = ~0ull;
    }
    if (tid < 2 * CMAX) comp_c[tid] = tid & (CMAX - 1);
    if (tid == 0) doneFlag[0] = 0;

    const int wave = threadIdx.x >> 6, lane = threadIdx.x & 63;
    const int row = blockIdx.x * 4 + wave;
    const float4* r1 = (const float4*)(x1 + (size_t)row * D);
    const float4* r2 = (const float4*)(x2 + (size_t)row * D);
    float4 a0 = r1[lane * 2], a1 = r1[lane * 2 + 1];
    float4 b0 = r2[lane * 2], b1 = r2[lane * 2 + 1];
    ushort4* o1 = (ushort4*)(h1 + (size_t)row * D + lane * 8);
    ushort4* o2 = (ushort4*)(h2 + (size_t)row * D + lane * 8);
    o1[0] = make_ushort4(__builtin_bit_cast(u16, (_Float16)a0.x), __builtin_bit_cast(u16, (_Float16)a0.y),
                         __builtin_bit_cast(u16, (_Float16)a0.z), __builtin_bit_cast(u16, (_Float16)a0.w));
    o1[1] = make_ushort4(__builtin_bit_cast(u16, (_Float16)a1.x), __builtin_bit_cast(u16, (_Float16)a1.y),
                         __builtin_bit_cast(u16, (_Float16)a1.z), __builtin_bit_cast(u16, (_Float16)a1.w));
    o2[0] = make_ushort4(__builtin_bit_cast(u16, (_Float16)b0.x), __builtin_bit_cast(u16, (_Float16)b0.y),
                         __builtin_bit_cast(u16, (_Float16)b0.z), __builtin_bit_cast(u16, (_Float16)b0.w));
    o2[1] = make_ushort4(__builtin_bit_cast(u16, (_Float16)b1.x), __builtin_bit_cast(u16, (_Float16)b1.y),
                         __builtin_bit_cast(u16, (_Float16)b1.z), __builtin_bit_cast(u16, (_Float16)b1.w));
    float s1 = 0.f, s2 = 0.f, sr = 0.f;
    float av[8] = {a0.x, a0.y, a0.z, a0.w, a1.x, a1.y, a1.z, a1.w};
    float bv[8] = {b0.x, b0.y, b0.z, b0.w, b1.x, b1.y, b1.z, b1.w};
#pragma unroll
    for (int e = 0; e < 8; ++e) {
        s1 = fmaf(av[e], av[e], s1);
        s2 = fmaf(bv[e], bv[e], s2);
        float d = av[e] - bv[e];
        sr = fmaf(d, d, sr);
    }
#pragma unroll
    for (int off = 32; off > 0; off >>= 1) {
        s1 += __shfl_down(s1, off, 64);
        s2 += __shfl_down(s2, off, 64);
        sr += __shfl_down(sr, off, 64);
    }
    __shared__ float wsr[4];
    if (lane == 0) {
        sq[row] = s1;
        sq[N + row] = s2;
        wsr[wave] = sr;
    }
    __syncthreads();
    if (threadIdx.x == 0)
        accumArr[blockIdx.x] = wsr[0] + wsr[1] + wsr[2] + wsr[3];
}

// ---------------- single-pass f16 MFMA GEMM + dist epilogue + fused round-1 row argmin
// SYMMETRIC triangle compute+store; COUNTED-VMCNT double-buffered K-loop (T4):
// raw s_barrier pairs (data-ready / reads-done), loads stay in flight across
// barriers; no vmcnt(0) drain in the steady-state loop. Bit-exact vs prior.
#define BM 128
#define BN 128
#define BK 32
#define NB (N / BM)          // 32 tile rows/cols
#define NPAIR (NB * (NB + 1) / 2)  // 528
#define NT (D / BK)          // 16

__global__ __launch_bounds__(256) void gemm_dist_sym_kernel(const u16* __restrict__ h1,
                                                            const u16* __restrict__ h2,
                                                            const float* __restrict__ sqn,
                                                            float* __restrict__ dist1,
                                                            float* __restrict__ dist2,
                                                            u64* __restrict__ compBest) {
    const int m = blockIdx.z;
    const u16* H = m ? h2 : h1;
    const float* SQ = sqn + (size_t)m * N;
    float* dist = m ? dist2 : dist1;
    u64* cb = compBest + (size_t)m * N;

    // decode linear pair index -> (by, bx), by <= bx
    const int t = blockIdx.x;
    int by = (int)((65.0f - sqrtf(4225.0f - 8.0f * (float)t)) * 0.5f);
    while (by > 0 && by * 32 - by * (by - 1) / 2 > t) --by;
    while ((by + 1) * 32 - (by + 1) * by / 2 <= t) ++by;
    const int bx = by + (t - (by * 32 - by * (by - 1) / 2));
    const bool diag = (by == bx);

    __shared__ u16 SH[4 * BM * BK];          // 32 KB: two (A,B) buffers
    u16* A0 = SH;
    u16* B0 = SH + BM * BK;
    u16* A1 = SH + 2 * BM * BK;
    u16* B1 = SH + 3 * BM * BK;

    const int tid = threadIdx.x;
    const int wave = tid >> 6, lane = tid & 63;
    const int wm = wave >> 1, wn = wave & 1;
    const int row0 = by * BM, col0 = bx * BN;

    floatx4 acc[4][4] = {};

    const int srow = lane >> 2;
    // swizzled source chunk: chunk' = (lane&3) ^ ((srow>>1)&3) = (lane&3) ^ ((lane>>3)&3)
    const int scol = (((lane & 3) ^ ((lane >> 3) & 3))) * 8;

#define STAGE(AB, BB, K0)                                                                      \
    {                                                                                          \
        _Pragma("unroll") for (int i_ = 0; i_ < 2; ++i_) {                                     \
            const int rb_ = wave * 32 + i_ * 16;                                               \
            const u16* ga_ = H + (size_t)(row0 + rb_ + srow) * D + (K0) + scol;                \
            __builtin_amdgcn_global_load_lds(                                                  \
                (const __attribute__((address_space(1))) unsigned int*)ga_,                    \
                (__attribute__((address_space(3))) unsigned int*)&(AB)[rb_ * BK], 16, 0, 0);   \
            if (!diag) {                                                                       \
                const u16* gb_ = H + (size_t)(col0 + rb_ + srow) * D + (K0) + scol;            \
                __builtin_amdgcn_global_load_lds(                                              \
                    (const __attribute__((address_space(1))) unsigned int*)gb_,                \
                    (__attribute__((address_space(3))) unsigned int*)&(BB)[rb_ * BK], 16, 0, 0); \
            }                                                                                  \
        }                                                                                      \
    }

    // prologue: stage both buffers; loads stay in flight.
    STAGE(A0, B0, 0);
    STAGE(A1, B1, BK);

    // swizzled read chunk for fragment row fm = lane&15: cs = (chunk ^ ((fm>>1)&3))*8
    const int cs = (((lane >> 4) ^ ((lane >> 1) & 3))) * 8;
    const int fm = lane & 15;
    for (int kt = 0; kt < NT; ++kt) {
        u16* Ac = (kt & 1) ? A1 : A0;
        u16* Bc = (kt & 1) ? B1 : B0;
        // counted wait: my stage-kt loads done; stage-(kt+1) (newest 4 or 2) stay in flight.
        if (kt < NT - 1) {
            if (diag) asm volatile("s_waitcnt vmcnt(2)" ::: "memory");
            else      asm volatile("s_waitcnt vmcnt(4)" ::: "memory");
        } else {
            asm volatile("s_waitcnt vmcnt(0)" ::: "memory");
        }
        __builtin_amdgcn_s_barrier();          // (1) data-ready: all waves' stage-kt landed
        __builtin_amdgcn_sched_barrier(0);
        const u16* Bs = diag ? Ac : Bc;
        f16x8 a8[4], b8[4];
#pragma unroll
        for (int s = 0; s < 4; ++s) {
            a8[s] = *(const f16x8*)&Ac[(wm * 64 + s * 16 + fm) * BK + cs];
            b8[s] = *(const f16x8*)&Bs[(wn * 64 + s * 16 + fm) * BK + cs];
        }
        asm volatile("s_waitcnt lgkmcnt(0)" ::: "memory");
        __builtin_amdgcn_sched_barrier(0);
        __builtin_amdgcn_s_barrier();          // (2) reads-done: safe to overwrite buffer
        if (kt + 2 < NT) {
            u16* An = (kt & 1) ? A1 : A0;      // same buffer just read
            u16* Bn = (kt & 1) ? B1 : B0;
            STAGE(An, Bn, (kt + 2) * BK);      // flies during MFMA + next iter
        }
#pragma unroll
        for (int i = 0; i < 4; ++i)
#pragma unroll
            for (int j = 0; j < 4; ++j)
                acc[i][j] = __builtin_amdgcn_mfma_f32_16x16x32_f16(a8[i], b8[j], acc[i][j], 0, 0, 0);
    }
#undef STAGE
    __syncthreads();   // drain + fence before SH reuse as Cs

    float* Cs = (float*)SH + wave * 1024;

    const int lr = lane & 15;
    const int lq = lane >> 4;
    float sc[4];
#pragma unroll
    for (int ns = 0; ns < 4; ++ns) sc[ns] = SQ[col0 + wn * 64 + ns * 16 + lr];
    u64 colBest[4] = {~0ull, ~0ull, ~0ull, ~0ull};
#pragma unroll
    for (int ms = 0; ms < 4; ++ms) {
        const int rb = row0 + wm * 64 + ms * 16 + lq * 4;
        float srow_[4];
#pragma unroll
        for (int r = 0; r < 4; ++r) srow_[r] = SQ[rb + r];
#pragma unroll
        for (int r = 0; r < 4; ++r) {
            const int row = rb + r;
            float dval[4];
#pragma unroll
            for (int ns = 0; ns < 4; ++ns) {
                const int col = col0 + wn * 64 + ns * 16 + lr;
                float d2 = srow_[r] + sc[ns] - 2.0f * acc[ms][ns][r];
                dval[ns] = (row == col) ? BIG : sqrtf(fmaxf(d2, 1e-12f));
            }
            float vmin = fminf(fminf(dval[0], dval[1]), fminf(dval[2], dval[3]));
            int nsel = (dval[0] == vmin) ? 0 : (dval[1] == vmin) ? 1 : (dval[2] == vmin) ? 2 : 3;
            u64 pmin = (((u64)__float_as_uint(vmin)) << 32) | (unsigned)(col0 + wn * 64 + nsel * 16 + lr);
#pragma unroll
            for (int msk = 1; msk < 16; msk <<= 1) {
                u64 o = __shfl_xor(pmin, msk, 64);
                pmin = o < pmin ? o : pmin;
            }
            if (lr == 0) atomicMin(&cb[row], pmin);
            if (!diag) {
#pragma unroll
                for (int ns = 0; ns < 4; ++ns) {
                    u64 p = (((u64)__float_as_uint(dval[ns])) << 32) | (unsigned)row;
                    colBest[ns] = p < colBest[ns] ? p : colBest[ns];
                }
            }
#pragma unroll
            for (int ns = 0; ns < 4; ++ns)
                Cs[(lq * 4 + r) * 64 + ns * 16 + lr] = dval[ns];
        }
        // triangle tile store only (rows of dist)
#pragma unroll
        for (int p = 0; p < 4; ++p) {
            float4 v4 = *(float4*)&Cs[p * 256 + lane * 4];
            const int gr = row0 + wm * 64 + ms * 16 + p * 4 + (lane >> 4);
            const int gc = col0 + wn * 64 + (lane & 15) * 4;
            *(float4*)&dist[(size_t)gr * N + gc] = v4;
        }
    }
    // column argmin -> compBest for the mirror rows (off-diagonal only)
    if (!diag) {
#pragma unroll
        for (int ns = 0; ns < 4; ++ns) {
            u64 b = colBest[ns];
            u64 o = __shfl_xor(b, 16, 64);
            b = o < b ? o : b;
            o = __shfl_xor(b, 32, 64);
            b = o < b ? o : b;
            if (lq == 0) atomicMin(&cb[col0 + wn * 64 + ns * 16 + lr], b);
        }
    }
}

// ---------------- merge round 1 (blocks 0,1) + distc +inf init (blocks 2..1025)
__global__ __launch_bounds__(1024) void merge1i_kernel(int* __restrict__ comp,
                                                       u64* __restrict__ compBest,
                                                       float* __restrict__ deaths,
                                                       int* __restrict__ cnt,
                                                       int* __restrict__ numComp,
                                                       int* __restrict__ numC1,
                                                       unsigned* __restrict__ distc_u) {
    const int t = threadIdx.x;
    if (blockIdx.x >= 2) {
        const size_t idx = (size_t)(blockIdx.x - 2) * 1024 + t;
        uint4 v = make_uint4(0x7f800000u, 0x7f800000u, 0x7f800000u, 0x7f800000u);
        ((uint4*)distc_u)[idx] = v;
        ((uint4*)distc_u)[idx + 1048576] = v;
        return;
    }
    const int m = blockIdx.x;
    int* cp = comp + (size_t)m * N;
    u64* cb = compBest + (size_t)m * N;
    float* dth = deaths + (size_t)m * N;

    __shared__ int pa[N];
    __shared__ int pb[N];
    __shared__ unsigned flagbits[NW];
    __shared__ int wpc[NW];
    __shared__ int done;

    if (t == 0) cnt[m] = 0;
    __syncthreads();

    for (int c = t; c < N; c += 1024) {
        u64 best = cb[c];
        int p = c;
        if (best != ~0ull) {
            int j = (int)(unsigned)best;
            int c2 = cp[j];
            u64 best2 = cb[c2];
            int j2 = (int)(unsigned)best2;
            bool mutual = (cp[j2] == c);
            if (!(mutual && c < c2)) {
                p = c2;
                int idx = atomicAdd(cnt + m, 1);
                dth[idx] = __uint_as_float((unsigned)(best >> 32));
            }
        }
        pa[c] = p;
    }

    int* A = pa;
    int* B = pb;
    while (true) {
        __syncthreads();
        if (t == 0) done = 1;
        __syncthreads();
        bool ch = false;
        for (int c = t; c < N; c += 1024) {
            int g = A[A[c]];
            B[c] = g;
            ch |= (g != A[c]);
        }
        if (ch) done = 0;
        __syncthreads();
        int* tmp = A; A = B; B = tmp;
        if (done) break;
    }

    for (int w = t; w < NW; w += 1024) flagbits[w] = 0u;
    __syncthreads();
    for (int i = t; i < N; i += 1024)
        atomicOr(&flagbits[A[i] >> 5], 1u << (A[i] & 31));
    __syncthreads();
    if (t < NW) wpc[t] = __popc(flagbits[t]);
    __syncthreads();
    for (int off = 1; off < NW; off <<= 1) {
        int v = 0;
        if (t < NW) v = wpc[t] + ((t >= off) ? wpc[t - off] : 0);
        __syncthreads();
        if (t < NW) wpc[t] = v;
        __syncthreads();
    }
    for (int i = t; i < N; i += 1024) {
        int root = A[i];
        int w = root >> 5, b = root & 31;
        int base = w ? wpc[w - 1] : 0;
        unsigned mask = b ? ((1u << b) - 1u) : 0u;
        cp[i] = base + __popc(flagbits[w] & mask);
    }
    for (int c = t; c < N; c += 1024) cb[c] = ~0ull;
    if (t == 0) {
        int C1 = wpc[NW - 1];
        numC1[m] = C1;
        numComp[m] = C1;
    }
}

// ---------------- atomic level-1 contraction, TRIANGLE reads only.
// One block per row (full parallelism — R5 lesson: never serialize rows per block).
// LDS bins restricted to ceil64(C1); flush via global atomicMin.
__global__ __launch_bounds__(256) void rowatomic_kernel(const float* __restrict__ dist1,
                                                        const float* __restrict__ dist2,
                                                        const int* __restrict__ comp,
                                                        const int* __restrict__ numC1,
                                                        unsigned* __restrict__ distc_u) {
    const int m = blockIdx.y;
    const int cend = (numC1[m] + 63) & ~63;
    const float* dist = m ? dist2 : dist1;
    const int* cp = comp + (size_t)m * N;
    const int i = blockIdx.x;
    const float4* row4 = (const float4*)(dist + (size_t)i * N);
    const int4* cp4 = (const int4*)cp;
    __shared__ unsigned bins[CMAX];
    const int t = threadIdx.x;
    for (int b = t; b < cend; b += 256) bins[b] = 0x7f800000u;
    __syncthreads();
    const int q0 = (i >> 7) << 5;   // float4 index of this row's diagonal-tile start
    for (int q = q0 + t; q < N / 4; q += 256) {
        float4 v = row4[q];
        int4 cj = cp4[q];
        atomicMin(&bins[cj.x], __float_as_uint(v.x));
        atomicMin(&bins[cj.y], __float_as_uint(v.y));
        atomicMin(&bins[cj.z], __float_as_uint(v.z));
        atomicMin(&bins[cj.w], __float_as_uint(v.w));
    }
    __syncthreads();
    unsigned* drow = distc_u + ((size_t)m * CMAX + cp[i]) * CMAX;
    for (int b = t; b < cend; b += 256) {
        unsigned v = bins[b];
        if (v != 0x7f800000u) atomicMin(&drow[b], v);
    }
}

// ---------------- FUSED symmetrize + round-2 scan + distc2 init
#define CT 64
#define NCT (CMAX / CT)                // 32
#define NPAIRC (NCT * (NCT + 1) / 2)   // 528
__global__ __launch_bounds__(256) void symscan_kernel(unsigned* __restrict__ distc_u,
                                                      u64* __restrict__ compBest,
                                                      const int* __restrict__ numComp,
                                                      const int* __restrict__ numC1,
                                                      unsigned* __restrict__ distc2_u) {
    const int tid = threadIdx.x;
    if (blockIdx.x >= NPAIRC) {
        // init distc2: 2*CMAX2*CMAX2 floats = 524,288 uint4; (256 blocks x 2 y) x 256 thr x 4
        const size_t base = ((size_t)blockIdx.y * 256 + (blockIdx.x - NPAIRC)) * 256 + tid;
        uint4 v = make_uint4(0x7f800000u, 0x7f800000u, 0x7f800000u, 0x7f800000u);
#pragma unroll
        for (int k = 0; k < 4; ++k)
            ((uint4*)distc2_u)[base + (size_t)k * 131072] = v;
        return;
    }
    const int m = blockIdx.y;
    if (numComp[m] <= 1) return;
    const int C1 = numC1[m];
    const int t = blockIdx.x;
    int a = (int)((65.0f - sqrtf(4225.0f - 8.0f * (float)t)) * 0.5f);
    while (a > 0 && a * 32 - a * (a - 1) / 2 > t) --a;
    while ((a + 1) * 32 - (a + 1) * a / 2 <= t) ++a;
    const int b = a + (t - (a * 32 - a * (a - 1) / 2));
    if (a * CT >= C1 || b * CT >= C1) return;   // all-inf region, never read downstream

    unsigned* Dm = distc_u + (size_t)m * CMAX * CMAX;
    unsigned* P = Dm + (size_t)(a * CT) * CMAX + b * CT;   // tile (a,b)
    unsigned* Q = Dm + (size_t)(b * CT) * CMAX + a * CT;   // tile (b,a)
    u64* cb = compBest + (size_t)m * N;

    __shared__ float L[CT][CT + 1];
    __shared__ float M[CT][CT + 1];
#pragma unroll
    for (int e0 = 0; e0 < 4; ++e0) {
        int e = e0 * 256 + tid;
        int r = e >> 4, c4 = (e & 15) << 2;
        float4 v = *(const float4*)&Q[(size_t)r * CMAX + c4];
        L[r][c4] = v.x; L[r][c4 + 1] = v.y; L[r][c4 + 2] = v.z; L[r][c4 + 3] = v.w;
    }
    __syncthreads();
#pragma unroll
    for (int e0 = 0; e0 < 4; ++e0) {
        int e = e0 * 256 + tid;
        int r = e >> 4, c4 = (e & 15) << 2;
        float4 v = *(const float4*)&P[(size_t)r * CMAX + c4];
        float4 f;
        f.x = fminf(v.x, L[c4 + 0][r]);
        f.y = fminf(v.y, L[c4 + 1][r]);
        f.z = fminf(v.z, L[c4 + 2][r]);
        f.w = fminf(v.w, L[c4 + 3][r]);
        *(float4*)&P[(size_t)r * CMAX + c4] = f;
        M[r][c4] = f.x; M[r][c4 + 1] = f.y; M[r][c4 + 2] = f.z; M[r][c4 + 3] = f.w;
    }
    __syncthreads();

    // direction 1: rows of tile a over cols of tile b (S rows)
    {
        const int rloc = tid >> 2;
        const int r = a * CT + rloc;
        const int c0 = (tid & 3) * 16;
        u64 best = ~0ull;
#pragma unroll
        for (int c = 0; c < 16; ++c) {
            const int j = b * CT + c0 + c;
            const unsigned bits = __float_as_uint(M[rloc][c0 + c]);
            if (j < C1 && j != r && bits < 0x7f800000u) {
                u64 p = (((u64)bits) << 32) | (unsigned)j;
                best = p < best ? p : best;
            }
        }
        u64 o = __shfl_xor(best, 1, 64); best = o < best ? o : best;
        o = __shfl_xor(best, 2, 64); best = o < best ? o : best;
        if ((tid & 3) == 0 && r < C1 && best != ~0ull) atomicMin(&cb[r], best);
    }

    if (a == b) return;

    // direction 2: rows of tile b over cols of tile a (S^T = M columns)
    {
        const int rloc = tid >> 2;
        const int r = b * CT + rloc;
        const int c0 = (tid & 3) * 16;
        u64 best = ~0ull;
#pragma unroll
        for (int c = 0; c < 16; ++c) {
            const int j = a * CT + c0 + c;
            const unsigned bits = __float_as_uint(M[c0 + c][rloc]);
            if (j < C1 && bits < 0x7f800000u) {   // j != r guaranteed (a != b)
                u64 p = (((u64)bits) << 32) | (unsigned)j;
                best = p < best ? p : best;
            }
        }
        u64 o = __shfl_xor(best, 1, 64); best = o < best ? o : best;
        o = __shfl_xor(best, 2, 64); best = o < best ? o : best;
        if ((tid & 3) == 0 && r < C1 && best != ~0ull) atomicMin(&cb[r], best);
    }

    // write back S^T to tile (b,a)
#pragma unroll
    for (int e0 = 0; e0 < 4; ++e0) {
        int e = e0 * 256 + tid;
        int r = e >> 4, c4 = (e & 15) << 2;
        float4 f;
        f.x = M[c4 + 0][r];
        f.y = M[c4 + 1][r];
        f.z = M[c4 + 2][r];
        f.w = M[c4 + 3][r];
        *(float4*)&Q[(size_t)r * CMAX + c4] = f;
    }
}

// ---------------- merge round 2 (trimmed): hook + jump + dense relabel + comp_c2 identity
__global__ __launch_bounds__(1024) void merge2_kernel(int* __restrict__ comp_c,
                                                      u64* __restrict__ compBest,
                                                      float* __restrict__ deaths,
                                                      int* __restrict__ cnt,
                                                      int* __restrict__ numComp,
                                                      const int* __restrict__ numC1,
                                                      int* __restrict__ numC2,
                                                      int* __restrict__ comp_c2) {
    const int m = blockIdx.x;
    const int t = threadIdx.x;
    const int C1 = numC1[m];
    int* cc2i = comp_c2 + (size_t)m * CMAX2;
    for (int c = t; c < CMAX2; c += 1024) cc2i[c] = c;
    if (numComp[m] <= 1) {
        if (t == 0) numC2[m] = numComp[m];
        return;
    }
    int* cc = comp_c + (size_t)m * CMAX;
    u64* cb = compBest + (size_t)m * N;
    float* dth = deaths + (size_t)m * N;

    __shared__ int pa[CMAX];
    __shared__ int pb[CMAX];
    __shared__ unsigned flagbits[CMAX / 32];
    __shared__ int wpc[CMAX / 32];
    __shared__ int done;

    for (int c = t; c < C1; c += 1024) {
        u64 best = cb[c];
        int p = c;
        if (best != ~0ull) {
            int j = (int)(unsigned)best;
            int c2 = cc[j];
            u64 best2 = cb[c2];
            int j2 = (int)(unsigned)best2;
            bool mutual = (cc[j2] == c);
            if (!(mutual && c < c2)) {
                p = c2;
                int idx = atomicAdd(cnt + m, 1);
                dth[idx] = __uint_as_float((unsigned)(best >> 32));
            }
        }
        pa[c] = p;
    }

    int* A = pa;
    int* B = pb;
    while (true) {
        __syncthreads();
        if (t == 0) done = 1;
        __syncthreads();
        bool ch = false;
        for (int c = t; c < C1; c += 1024) {
            int g = A[A[c]];
            B[c] = g;
            ch |= (g != A[c]);
        }
        if (ch) done = 0;
        __syncthreads();
        int* tmp = A; A = B; B = tmp;
        if (done) break;
    }

    for (int w = t; w < CMAX / 32; w += 1024) flagbits[w] = 0u;
    __syncthreads();
    for (int j = t; j < C1; j += 1024)
        atomicOr(&flagbits[A[j] >> 5], 1u << (A[j] & 31));
    __syncthreads();
    if (t < CMAX / 32) wpc[t] = __popc(flagbits[t]);
    __syncthreads();
    for (int off = 1; off < CMAX / 32; off <<= 1) {
        int v = 0;
        if (t < CMAX / 32) v = wpc[t] + ((t >= off) ? wpc[t - off] : 0);
        __syncthreads();
        if (t < CMAX / 32) wpc[t] = v;
        __syncthreads();
    }
    for (int j = t; j < C1; j += 1024) {
        int root = A[j];
        int w = root >> 5, b = root & 31;
        int base = w ? wpc[w - 1] : 0;
        unsigned mask = b ? ((1u << b) - 1u) : 0u;
        cc[j] = base + __popc(flagbits[w] & mask);
    }
    for (int c = t; c < C1; c += 1024) cb[c] = ~0ull;
    if (t == 0) {
        int C2 = wpc[CMAX / 32 - 1];
        numC2[m] = C2;
        numComp[m] = C2;
    }
}

// ---------------- atomic level-2 contraction: row of distc -> bins[C2] -> distc2
__global__ __launch_bounds__(256) void rowatomic2_kernel(const float* __restrict__ distc,
                                                         const int* __restrict__ comp_c,
                                                         const int* __restrict__ numComp,
                                                         const int* __restrict__ numC1,
                                                         unsigned* __restrict__ distc2_u) {
    const int m = blockIdx.y;
    if (numComp[m] <= 1) return;
    const int C1 = numC1[m];
    const int r = blockIdx.x;
    if (r >= C1) return;
    const int* cc = comp_c + (size_t)m * CMAX;
    const float* row = distc + ((size_t)m * CMAX + r) * CMAX;
    __shared__ unsigned bins[CMAX2];
    const int t = threadIdx.x;
    for (int b = t; b < CMAX2; b += 256) bins[b] = 0x7f800000u;
    __syncthreads();
    for (int j = t; j < C1; j += 256)
        atomicMin(&bins[cc[j]], __float_as_uint(row[j]));
    __syncthreads();
    unsigned* drow = distc2_u + ((size_t)m * CMAX2 + cc[r]) * CMAX2;
    for (int b = t; b < CMAX2; b += 256) {
        unsigned v = bins[b];
        if (v != 0x7f800000u) atomicMin(&drow[b], v);
    }
}

// ---------------- level-3 scan over distc2 (blocks < 2*CMAX2) + distc3 +inf init (rest)
__global__ __launch_bounds__(256) void scan3_kernel(const float* __restrict__ distc2,
                                                    const int* __restrict__ comp_c2,
                                                    u64* __restrict__ compBest,
                                                    const int* __restrict__ numComp,
                                                    const int* __restrict__ numC2,
                                                    unsigned* __restrict__ distc3_u) {
    const int t = threadIdx.x;
    if (blockIdx.x >= 2 * CMAX2) {
        // init distc3: 2*512*512 floats = 131072 uint4; 256 blocks x 256 thr x 2
        const size_t idx = (size_t)(blockIdx.x - 2 * CMAX2) * 256 + t;
        uint4 v = make_uint4(0x7f800000u, 0x7f800000u, 0x7f800000u, 0x7f800000u);
        ((uint4*)distc3_u)[idx] = v;
        ((uint4*)distc3_u)[idx + 65536] = v;
        return;
    }
    const int m = blockIdx.x >> 10;          // CMAX2 = 1024
    if (numComp[m] <= 1) return;
    const int C2 = numC2[m];
    const int r = blockIdx.x & (CMAX2 - 1);
    if (r >= C2) return;
    const int* cc = comp_c2 + (size_t)m * CMAX2;
    u64* cb = compBest + (size_t)m * N;
    const int myc = cc[r];
    const float4* row4 = (const float4*)(distc2 + ((size_t)m * CMAX2 + r) * CMAX2);
    const int4* cc4 = (const int4*)cc;
    float4 v = row4[t];
    int4 cj = cc4[t];
    int j0 = t * 4;
    u64 p0 = (j0 + 0 < C2 && cj.x != myc) ? ((((u64)__float_as_uint(v.x)) << 32) | (unsigned)(j0 + 0)) : ~0ull;
    u64 p1 = (j0 + 1 < C2 && cj.y != myc) ? ((((u64)__float_as_uint(v.y)) << 32) | (unsigned)(j0 + 1)) : ~0ull;
    u64 p2 = (j0 + 2 < C2 && cj.z != myc) ? ((((u64)__float_as_uint(v.z)) << 32) | (unsigned)(j0 + 2)) : ~0ull;
    u64 p3 = (j0 + 3 < C2 && cj.w != myc) ? ((((u64)__float_as_uint(v.w)) << 32) | (unsigned)(j0 + 3)) : ~0ull;
    u64 q0 = p0 < p1 ? p0 : p1;
    u64 q1 = p2 < p3 ? p2 : p3;
    u64 best = q0 < q1 ? q0 : q1;
#pragma unroll
    for (int off = 32; off > 0; off >>= 1) {
        u64 o = __shfl_down(best, off, 64);
        best = o < best ? o : best;
    }
    if ((t & 63) == 0) atomicMin(cb + myc, best);
}

// ---------------- merge round 3: hook + jump + dense relabel of comp_c2
__global__ __launch_bounds__(1024) void merge3_kernel(int* __restrict__ comp_c2,
                                                      u64* __restrict__ compBest,
                                                      float* __restrict__ deaths,
                                                      int* __restrict__ cnt,
                                                      int* __restrict__ numComp,
                                                      const int* __restrict__ numC2,
                                                      int* __restrict__ numC3) {
    const int m = blockIdx.x;
    const int t = threadIdx.x;
    if (numComp[m] <= 1) {
        if (t == 0) numC3[m] = numComp[m];
        return;
    }
    const int C2 = numC2[m];
    int* cc = comp_c2 + (size_t)m * CMAX2;
    u64* cb = compBest + (size_t)m * N;
    float* dth = deaths + (size_t)m * N;

    __shared__ int pa[CMAX2];
    __shared__ int pb[CMAX2];
    __shared__ unsigned flagbits[CMAX2 / 32];
    __shared__ int wpc[CMAX2 / 32];
    __shared__ int done;

    for (int c = t; c < C2; c += 1024) {
        u64 best = cb[c];
        int p = c;
        if (best != ~0ull) {
            int j = (int)(unsigned)best;
            int c2 = cc[j];
            u64 best2 = cb[c2];
            int j2 = (int)(unsigned)best2;
            bool mutual = (cc[j2] == c);
            if (!(mutual && c < c2)) {
                p = c2;
                int idx = atomicAdd(cnt + m, 1);
                dth[idx] = __uint_as_float((unsigned)(best >> 32));
            }
        }
        pa[c] = p;
    }

    int* A = pa;
    int* B = pb;
    while (true) {
        __syncthreads();
        if (t == 0) done = 1;
        __syncthreads();
        bool ch = false;
        for (int c = t; c < C2; c += 1024) {
            int g = A[A[c]];
            B[c] = g;
            ch |= (g != A[c]);
        }
        if (ch) done = 0;
        __syncthreads();
        int* tmp = A; A = B; B = tmp;
        if (done) break;
    }

    for (int w = t; w < CMAX2 / 32; w += 1024) flagbits[w] = 0u;
    __syncthreads();
    for (int j = t; j < C2; j += 1024)
        atomicOr(&flagbits[A[j] >> 5], 1u << (A[j] & 31));
    __syncthreads();
    if (t < CMAX2 / 32) wpc[t] = __popc(flagbits[t]);
    __syncthreads();
    for (int off = 1; off < CMAX2 / 32; off <<= 1) {
        int v = 0;
        if (t < CMAX2 / 32) v = wpc[t] + ((t >= off) ? wpc[t - off] : 0);
        __syncthreads();
        if (t < CMAX2 / 32) wpc[t] = v;
        __syncthreads();
    }
    for (int j = t; j < C2; j += 1024) {
        int root = A[j];
        int w = root >> 5, b = root & 31;
        int base = w ? wpc[w - 1] : 0;
        unsigned mask = b ? ((1u << b) - 1u) : 0u;
        cc[j] = base + __popc(flagbits[w] & mask);
    }
    for (int c = t; c < C2; c += 1024) cb[c] = ~0ull;
    if (t == 0) {
        int C3 = wpc[CMAX2 / 32 - 1];
        numC3[m] = C3;
        numComp[m] = C3;
    }
}

// ---------------- atomic level-3 contraction: row of distc2 -> bins[C3] -> distc3
__global__ __launch_bounds__(256) void rowatomic3_kernel(const float* __restrict__ distc2,
                                                         const int* __restrict__ comp_c2,
                                                         const int* __restrict__ numComp,
                                                         const int* __restrict__ numC2,
                                                         unsigned* __restrict__ distc3_u) {
    const int m = blockIdx.y;
    if (numComp[m] <= 1) return;
    const int C2 = numC2[m];
    const int r = blockIdx.x;
    if (r >= C2) return;
    const int* cc = comp_c2 + (size_t)m * CMAX2;
    const float* row = distc2 + ((size_t)m * CMAX2 + r) * CMAX2;
    __shared__ unsigned bins[CMAX3];
    const int t = threadIdx.x;
    for (int b = t; b < CMAX3; b += 256) bins[b] = 0x7f800000u;
    __syncthreads();
    for (int j = t; j < C2; j += 256)
        atomicMin(&bins[cc[j]], __float_as_uint(row[j]));
    __syncthreads();
    unsigned* drow = distc3_u + ((size_t)m * CMAX3 + cc[r]) * CMAX3;
    for (int b = t; b < CMAX3; b += 256) {
        unsigned v = bins[b];
        if (v != 0x7f800000u) atomicMin(&drow[b], v);
    }
}

// ---------------- finish: rounds >= 4 on distc3 + register-bitonic sort + fused final
__global__ __launch_bounds__(1024) void finish_kernel(const float* __restrict__ distc3,
                                                      float* __restrict__ deaths,
                                                      int* __restrict__ cnt,
                                                      int* __restrict__ numComp,
                                                      const int* __restrict__ numC3,
                                                      const float* __restrict__ accumArr,
                                                      int* __restrict__ doneFlag,
                                                      float* __restrict__ out) {
    const int m = blockIdx.x;
    int nc = numComp[m];
    const int C3 = numC3[m];
    const float* Dm = distc3 + (size_t)m * CMAX3 * CMAX3;
    float* dth = deaths + (size_t)m * N;
    const int t = threadIdx.x;
    const int wave = t >> 6, lane = t & 63;
    __shared__ int comp[CMAX3];
    __shared__ u64 cb[CMAX3];
    __shared__ int pa[CMAX3];
    __shared__ int pb[CMAX3];
    __shared__ unsigned flags[CMAX3 / 32];
    __shared__ int done, ncs, lastf;
    __shared__ float s[N];
    __shared__ float wsum[16];
    __shared__ float rsum[16];

    if (nc > 1) {
        for (int c = t; c < C3; c += 1024) {
            comp[c] = c;
            cb[c] = ~0ull;
        }
        __syncthreads();

        for (int round = 0; round < 10 && nc > 1; ++round) {
            for (int r = wave; r < C3; r += 16) {
                const int myc = comp[r];
                const float* row = Dm + (size_t)r * CMAX3;
                u64 best = ~0ull;
                for (int j = lane; j < C3; j += 64) {
                    if (comp[j] != myc) {
                        u64 p = (((u64)__float_as_uint(row[j])) << 32) | (unsigned)j;
                        best = p < best ? p : best;
                    }
                }
#pragma unroll
                for (int off = 32; off > 0; off >>= 1) {
                    u64 o = __shfl_down(best, off, 64);
                    best = o < best ? o : best;
                }
                if (lane == 0) atomicMin(&cb[myc], best);
            }
            __syncthreads();
            for (int c = t; c < C3; c += 1024) {
                u64 best = cb[c];
                int p = c;
                if (best != ~0ull) {
                    int j = (int)(unsigned)best;
                    int c2 = comp[j];
                    u64 best2 = cb[c2];
                    int j2 = (int)(unsigned)best2;
                    bool mutual = (comp[j2] == c);
                    if (!(mutual && c < c2)) {
                        p = c2;
                        int idx = atomicAdd(cnt + m, 1);
                        dth[idx] = __uint_as_float((unsigned)(best >> 32));
                    }
                }
                pa[c] = p;
            }
            int* A = pa; int* B = pb;
            while (true) {
                __syncthreads();
                if (t == 0) done = 1;
                __syncthreads();
                bool ch = false;
                for (int c = t; c < C3; c += 1024) {
                    int g = A[A[c]];
                    B[c] = g;
                    ch |= (g != A[c]);
                }
                if (ch) done = 0;
                __syncthreads();
                int* tmp = A; A = B; B = tmp;
                if (done) break;
            }
            for (int w = t; w < CMAX3 / 32; w += 1024) flags[w] = 0u;
            __syncthreads();
            for (int j = t; j < C3; j += 1024) {
                int root = A[comp[j]];
                comp[j] = root;
                atomicOr(&flags[root >> 5], 1u << (root & 31));
            }
            for (int c = t; c < C3; c += 1024) cb[c] = ~0ull;
            __syncthreads();
            if (t == 0) {
                int sacc = 0;
                for (int w = 0; w < CMAX3 / 32; ++w) sacc += __popc(flags[w]);
                ncs = sacc;
            }
            __syncthreads();
            nc = ncs;
        }
        if (t == 0) numComp[m] = nc;
    }
    __syncthreads();

    // ---- register-resident bitonic sort (ascending) of the 4096 deaths.
    const int t4 = t << 2;
    float v0, v1, v2, v3;
    {
        float4 l4 = *(const float4*)&dth[t4];
        v0 = l4.x; v1 = l4.y; v2 = l4.z; v3 = l4.w;
        if (t == 1023) v3 = BIG;   // element N-1 pad
    }
#define CSWAP(a, b, up)                         \
    {                                           \
        float mn_ = fminf(a, b), mx_ = fmaxf(a, b); \
        a = (up) ? mn_ : mx_;                   \
        b = (up) ? mx_ : mn_;                   \
    }
    for (int k = 2; k <= N; k <<= 1) {
        for (int jj = k >> 1; jj > 0; jj >>= 1) {
            if (jj >= 256) {
                s[t4] = v0; s[t4 + 1] = v1; s[t4 + 2] = v2; s[t4 + 3] = v3;
                __syncthreads();
                const bool up = ((t4 & k) == 0);
                const bool lower = ((t4 & jj) == 0);
                const bool mk = (up == lower);
                float o0 = s[t4 ^ jj], o1 = s[(t4 + 1) ^ jj];
                float o2 = s[(t4 + 2) ^ jj], o3 = s[(t4 + 3) ^ jj];
                v0 = mk ? fminf(v0, o0) : fmaxf(v0, o0);
                v1 = mk ? fminf(v1, o1) : fmaxf(v1, o1);
                v2 = mk ? fminf(v2, o2) : fmaxf(v2, o2);
                v3 = mk ? fminf(v3, o3) : fmaxf(v3, o3);
                __syncthreads();
            } else if (jj >= 4) {
                const int sl = jj >> 2;
                const bool up = ((t4 & k) == 0);
                const bool lower = ((lane & sl) == 0);
                const bool mk = (up == lower);
                float o0 = __shfl_xor(v0, sl, 64);
                float o1 = __shfl_xor(v1, sl, 64);
                float o2 = __shfl_xor(v2, sl, 64);
                float o3 = __shfl_xor(v3, sl, 64);
                v0 = mk ? fminf(v0, o0) : fmaxf(v0, o0);
                v1 = mk ? fminf(v1, o1) : fmaxf(v1, o1);
                v2 = mk ? fminf(v2, o2) : fmaxf(v2, o2);
                v3 = mk ? fminf(v3, o3) : fmaxf(v3, o3);
            } else if (jj == 2) {
                const bool up = ((t4 & k) == 0);
                CSWAP(v0, v2, up);
                CSWAP(v1, v3, up);
            } else {
                const bool u01 = ((t4 & k) == 0);
                const bool u23 = (((t4 + 2) & k) == 0);
                CSWAP(v0, v1, u01);
                CSWAP(v2, v3, u23);
            }
        }
    }
#undef CSWAP
    *(float4*)&dth[t4] = make_float4(v0, v1, v2, v3);

    // last-block fused final (device-scope ticket; grid-order independent)
    __threadfence();
    __syncthreads();
    if (t == 0) lastf = (atomicAdd(doneFlag, 1) == 1) ? 1 : 0;
    __syncthreads();
    if (!lastf) return;
    __threadfence();
    const float* s1 = deaths;
    const float* s2 = deaths + N;
    float sum = 0.f;
    for (int i = t; i < N - 1; i += 1024) {
        float a = s1[i], b = s2[i];
        sum += fminf(fabsf(a - b), 0.5f * (a + b));
    }
    float ra = accumArr[t];
#pragma unroll
    for (int off = 32; off > 0; off >>= 1) {
        sum += __shfl_down(sum, off, 64);
        ra += __shfl_down(ra, off, 64);
    }
    if (lane == 0) { wsum[wave] = sum; rsum[wave] = ra; }
    __syncthreads();
    if (t == 0) {
        float tot = 0.f, rt = 0.f;
        for (int k = 0; k < 16; ++k) { tot += wsum[k]; rt += rsum[k]; }
        out[0] = rt * (1.0f / ((float)N * (float)D)) + tot;
    }
}

extern "C" void kernel_launch(void* const* d_in, const int* in_sizes, int n_in,
                              void* d_out, int out_size, void* d_ws, size_t ws_size,
                              hipStream_t stream) {
    const float* x1 = (const float*)d_in[0];
    const float* x2 = (const float*)d_in[1];
    float* out = (float*)d_out;
    float* ws = (float*)d_ws;

    const size_t nn = (size_t)N * N;
    const size_t cc2 = (size_t)CMAX * CMAX;

    float* dist1 = ws;
    float* dist2 = ws + nn;
    float* distc = ws + 2 * nn;
    u16* h1 = (u16*)distc;                 // alias: dead before merge1i's init overwrites
    u16* h2 = h1 + (size_t)N * D;
    u64* compBest = (u64*)(distc + 2 * cc2);
    int* comp      = (int*)(compBest + 2 * N);
    int* comp_c    = comp + 2 * N;
    float* deaths  = (float*)(comp_c + 2 * CMAX);
    int* cnt       = (int*)(deaths + 2 * N);
    int* numComp   = cnt + 2;
    int* numC1     = numComp + 2;
    int* numC2     = numC1 + 2;
    int* numC3     = numC2 + 2;
    int* doneFlag  = numC3 + 2;
    float* sq      = (float*)(doneFlag + 2);
    float* accumArr = sq + 2 * N;          // 1024 floats
    // level-2 buffers alias dist1 (dead after rowatomic) — distc2 init'd in symscan's
    // extra blocks, comp_c2 in merge2. Level-3 distc3 aliases distc (dead after
    // rowatomic2), init'd in scan3's extra blocks. NEVER earlier.
    float* distc2  = dist1;
    int* comp_c2   = (int*)(distc2 + 2 * (size_t)CMAX2 * CMAX2);
    float* distc3  = distc;

    prep_kernel<<<N / 4, 256, 0, stream>>>(x1, x2, h1, h2, sq, accumArr, comp, compBest,
                                           comp_c, doneFlag);
    gemm_dist_sym_kernel<<<dim3(NPAIR, 1, 2), 256, 0, stream>>>(h1, h2, sq, dist1, dist2, compBest);
    merge1i_kernel<<<2 + 1024, 1024, 0, stream>>>(comp, compBest, deaths, cnt, numComp, numC1,
                                                  (unsigned*)distc);
    rowatomic_kernel<<<dim3(N, 2), 256, 0, stream>>>(dist1, dist2, comp, numC1, (unsigned*)distc);
    symscan_kernel<<<dim3(NPAIRC + 256, 2), 256, 0, stream>>>((unsigned*)distc, compBest,
                                                              numComp, numC1, (unsigned*)distc2);
    merge2_kernel<<<2, 1024, 0, stream>>>(comp_c, compBest, deaths, cnt, numComp, numC1, numC2,
                                          comp_c2);
    rowatomic2_kernel<<<dim3(CMAX, 2), 256, 0, stream>>>(distc, comp_c, numComp, numC1,
                                                         (unsigned*)distc2);
    scan3_kernel<<<2 * CMAX2 + 256, 256, 0, stream>>>(distc2, comp_c2, compBest, numComp, numC2,
                                                      (unsigned*)distc3);
    merge3_kernel<<<2, 1024, 0, stream>>>(comp_c2, compBest, deaths, cnt, numComp, numC2, numC3);
    rowatomic3_kernel<<<dim3(CMAX2, 2), 256, 0, stream>>>(distc2, comp_c2, numComp, numC2,
                                                          (unsigned*)distc3);
    finish_kernel<<<2, 1024, 0, stream>>>(distc3, deaths, cnt, numComp, numC3,
                                          accumArr, doneFlag, out);
}

// Round 8
// 213.945 us; speedup vs baseline: 2.5456x; 1.0095x over previous
//
#include <hip/hip_runtime.h>

#define N 4096
#define D 512
#define BIG 1e30f
#define CMAX 2048
#define CMAX2 1024
#define CMAX3 512
#define NW (N / 32)

typedef unsigned long long u64;
typedef unsigned short u16;
typedef _Float16 f16x8 __attribute__((ext_vector_type(8)));
typedef float floatx4 __attribute__((ext_vector_type(4)));

// ---------------- fused prep: f32->f16 convert + row sq-norms + repr partial + init
__global__ __launch_bounds__(256) void prep_kernel(const float* __restrict__ x1,
                                                   const float* __restrict__ x2,
                                                   u16* __restrict__ h1,
                                                   u16* __restrict__ h2,
                                                   float* __restrict__ sq,
                                                   float* __restrict__ accumArr,
                                                   int* __restrict__ comp,
                                                   u64* __restrict__ compBest,
                                                   int* __restrict__ comp_c,
                                                   int* __restrict__ doneFlag) {
    const int tid = blockIdx.x * 256 + threadIdx.x;
    if (tid < 2 * N) {
        comp[tid] = tid & (N - 1);
        compBest[tid] = ~0ull;
    }
    if (tid < 2 * CMAX) comp_c[tid] = tid & (CMAX - 1);
    if (tid == 0) doneFlag[0] = 0;

    const int wave = threadIdx.x >> 6, lane = threadIdx.x & 63;
    const int row = blockIdx.x * 4 + wave;
    const float4* r1 = (const float4*)(x1 + (size_t)row * D);
    const float4* r2 = (const float4*)(x2 + (size_t)row * D);
    float4 a0 = r1[lane * 2], a1 = r1[lane * 2 + 1];
    float4 b0 = r2[lane * 2], b1 = r2[lane * 2 + 1];
    ushort4* o1 = (ushort4*)(h1 + (size_t)row * D + lane * 8);
    ushort4* o2 = (ushort4*)(h2 + (size_t)row * D + lane * 8);
    o1[0] = make_ushort4(__builtin_bit_cast(u16, (_Float16)a0.x), __builtin_bit_cast(u16, (_Float16)a0.y),
                         __builtin_bit_cast(u16, (_Float16)a0.z), __builtin_bit_cast(u16, (_Float16)a0.w));
    o1[1] = make_ushort4(__builtin_bit_cast(u16, (_Float16)a1.x), __builtin_bit_cast(u16, (_Float16)a1.y),
                         __builtin_bit_cast(u16, (_Float16)a1.z), __builtin_bit_cast(u16, (_Float16)a1.w));
    o2[0] = make_ushort4(__builtin_bit_cast(u16, (_Float16)b0.x), __builtin_bit_cast(u16, (_Float16)b0.y),
                         __builtin_bit_cast(u16, (_Float16)b0.z), __builtin_bit_cast(u16, (_Float16)b0.w));
    o2[1] = make_ushort4(__builtin_bit_cast(u16, (_Float16)b1.x), __builtin_bit_cast(u16, (_Float16)b1.y),
                         __builtin_bit_cast(u16, (_Float16)b1.z), __builtin_bit_cast(u16, (_Float16)b1.w));
    float s1 = 0.f, s2 = 0.f, sr = 0.f;
    float av[8] = {a0.x, a0.y, a0.z, a0.w, a1.x, a1.y, a1.z, a1.w};
    float bv[8] = {b0.x, b0.y, b0.z, b0.w, b1.x, b1.y, b1.z, b1.w};
#pragma unroll
    for (int e = 0; e < 8; ++e) {
        s1 = fmaf(av[e], av[e], s1);
        s2 = fmaf(bv[e], bv[e], s2);
        float d = av[e] - bv[e];
        sr = fmaf(d, d, sr);
    }
#pragma unroll
    for (int off = 32; off > 0; off >>= 1) {
        s1 += __shfl_down(s1, off, 64);
        s2 += __shfl_down(s2, off, 64);
        sr += __shfl_down(sr, off, 64);
    }
    __shared__ float wsr[4];
    if (lane == 0) {
        sq[row] = s1;
        sq[N + row] = s2;
        wsr[wave] = sr;
    }
    __syncthreads();
    if (threadIdx.x == 0)
        accumArr[blockIdx.x] = wsr[0] + wsr[1] + wsr[2] + wsr[3];
}

// ---------------- single-pass f16 MFMA GEMM + dist epilogue + fused round-1 row argmin
// SYMMETRIC triangle compute+store; 3-BUFFER SINGLE-BARRIER K-loop:
// one data-ready s_barrier per K-step. Safety: a wave's lgkmcnt(0) for tile t-1
// precedes its arrival at barrier(t), so at barrier(t) buf[t-1] is fully read ->
// STAGE(t+2) may overwrite it. Counted vmcnt (4 off-diag / 2 diag) keeps the
// next stage in flight across the barrier. Bit-exact vs prior.
#define BM 128
#define BN 128
#define BK 32
#define NB (N / BM)          // 32 tile rows/cols
#define NPAIR (NB * (NB + 1) / 2)  // 528
#define NT (D / BK)          // 16

__global__ __launch_bounds__(256) void gemm_dist_sym_kernel(const u16* __restrict__ h1,
                                                            const u16* __restrict__ h2,
                                                            const float* __restrict__ sqn,
                                                            float* __restrict__ dist1,
                                                            float* __restrict__ dist2,
                                                            u64* __restrict__ compBest) {
    const int m = blockIdx.z;
    const u16* H = m ? h2 : h1;
    const float* SQ = sqn + (size_t)m * N;
    float* dist = m ? dist2 : dist1;
    u64* cb = compBest + (size_t)m * N;

    // decode linear pair index -> (by, bx), by <= bx
    const int t = blockIdx.x;
    int by = (int)((65.0f - sqrtf(4225.0f - 8.0f * (float)t)) * 0.5f);
    while (by > 0 && by * 32 - by * (by - 1) / 2 > t) --by;
    while ((by + 1) * 32 - (by + 1) * by / 2 <= t) ++by;
    const int bx = by + (t - (by * 32 - by * (by - 1) / 2));
    const bool diag = (by == bx);

    __shared__ u16 SH[6 * BM * BK];          // 48 KB: three (A,B) buffers
    u16* const AB[3] = {SH, SH + 2 * BM * BK, SH + 4 * BM * BK};   // A at +0, B at +BM*BK

    const int tid = threadIdx.x;
    const int wave = tid >> 6, lane = tid & 63;
    const int wm = wave >> 1, wn = wave & 1;
    const int row0 = by * BM, col0 = bx * BN;

    floatx4 acc[4][4] = {};

    const int srow = lane >> 2;
    // swizzled source chunk: chunk' = (lane&3) ^ ((srow>>1)&3) = (lane&3) ^ ((lane>>3)&3)
    const int scol = (((lane & 3) ^ ((lane >> 3) & 3))) * 8;

#define STAGE(BASE, K0)                                                                        \
    {                                                                                          \
        u16* A_ = (BASE);                                                                      \
        u16* B_ = (BASE) + BM * BK;                                                            \
        _Pragma("unroll") for (int i_ = 0; i_ < 2; ++i_) {                                     \
            const int rb_ = wave * 32 + i_ * 16;                                               \
            const u16* ga_ = H + (size_t)(row0 + rb_ + srow) * D + (K0) + scol;                \
            __builtin_amdgcn_global_load_lds(                                                  \
                (const __attribute__((address_space(1))) unsigned int*)ga_,                    \
                (__attribute__((address_space(3))) unsigned int*)&A_[rb_ * BK], 16, 0, 0);     \
            if (!diag) {                                                                       \
                const u16* gb_ = H + (size_t)(col0 + rb_ + srow) * D + (K0) + scol;            \
                __builtin_amdgcn_global_load_lds(                                              \
                    (const __attribute__((address_space(1))) unsigned int*)gb_,                \
                    (__attribute__((address_space(3))) unsigned int*)&B_[rb_ * BK], 16, 0, 0); \
            }                                                                                  \
        }                                                                                      \
    }

    // prologue: stage tiles 0 and 1; loads stay in flight.
    STAGE(AB[0], 0);
    STAGE(AB[1], BK);
    u16* cur = AB[0];    // holds tile kt
    u16* nxt = AB[1];    // holds tile kt+1 (in flight)
    u16* fre = AB[2];    // free: target for tile kt+2

    // swizzled read chunk for fragment row fm = lane&15: cs = (chunk ^ ((fm>>1)&3))*8
    const int cs = (((lane >> 4) ^ ((lane >> 1) & 3))) * 8;
    const int fm = lane & 15;
    for (int kt = 0; kt < NT; ++kt) {
        // counted wait: my stage-kt loads done; stage-(kt+1) (newest 4 or 2) stay in flight.
        if (kt < NT - 1) {
            if (diag) asm volatile("s_waitcnt vmcnt(2)" ::: "memory");
            else      asm volatile("s_waitcnt vmcnt(4)" ::: "memory");
        } else {
            asm volatile("s_waitcnt vmcnt(0)" ::: "memory");
        }
        __builtin_amdgcn_s_barrier();          // data-ready(kt); also proves buf(kt-1) fully read
        __builtin_amdgcn_sched_barrier(0);
        if (kt + 2 < NT) STAGE(fre, (kt + 2) * BK);   // overwrite buf(kt-1): safe per barrier arg
        const u16* Ac = cur;
        const u16* Bs = diag ? cur : (cur + BM * BK);
        f16x8 a8[4], b8[4];
#pragma unroll
        for (int s = 0; s < 4; ++s) {
            a8[s] = *(const f16x8*)&Ac[(wm * 64 + s * 16 + fm) * BK + cs];
            b8[s] = *(const f16x8*)&Bs[(wn * 64 + s * 16 + fm) * BK + cs];
        }
        asm volatile("s_waitcnt lgkmcnt(0)" ::: "memory");
        __builtin_amdgcn_sched_barrier(0);
#pragma unroll
        for (int i = 0; i < 4; ++i)
#pragma unroll
            for (int j = 0; j < 4; ++j)
                acc[i][j] = __builtin_amdgcn_mfma_f32_16x16x32_f16(a8[i], b8[j], acc[i][j], 0, 0, 0);
        // rotate buffers: cur->free, nxt->cur, free->nxt
        u16* tmp = cur; cur = nxt; nxt = fre; fre = tmp;
    }
#undef STAGE
    __syncthreads();   // drain + fence before SH reuse as Cs

    float* Cs = (float*)SH + wave * 1024;

    const int lr = lane & 15;
    const int lq = lane >> 4;
    float sc[4];
#pragma unroll
    for (int ns = 0; ns < 4; ++ns) sc[ns] = SQ[col0 + wn * 64 + ns * 16 + lr];
    u64 colBest[4] = {~0ull, ~0ull, ~0ull, ~0ull};
#pragma unroll
    for (int ms = 0; ms < 4; ++ms) {
        const int rb = row0 + wm * 64 + ms * 16 + lq * 4;
        float srow_[4];
#pragma unroll
        for (int r = 0; r < 4; ++r) srow_[r] = SQ[rb + r];
#pragma unroll
        for (int r = 0; r < 4; ++r) {
            const int row = rb + r;
            float dval[4];
#pragma unroll
            for (int ns = 0; ns < 4; ++ns) {
                const int col = col0 + wn * 64 + ns * 16 + lr;
                float d2 = srow_[r] + sc[ns] - 2.0f * acc[ms][ns][r];
                dval[ns] = (row == col) ? BIG : sqrtf(fmaxf(d2, 1e-12f));
            }
            float vmin = fminf(fminf(dval[0], dval[1]), fminf(dval[2], dval[3]));
            int nsel = (dval[0] == vmin) ? 0 : (dval[1] == vmin) ? 1 : (dval[2] == vmin) ? 2 : 3;
            u64 pmin = (((u64)__float_as_uint(vmin)) << 32) | (unsigned)(col0 + wn * 64 + nsel * 16 + lr);
#pragma unroll
            for (int msk = 1; msk < 16; msk <<= 1) {
                u64 o = __shfl_xor(pmin, msk, 64);
                pmin = o < pmin ? o : pmin;
            }
            if (lr == 0) atomicMin(&cb[row], pmin);
            if (!diag) {
#pragma unroll
                for (int ns = 0; ns < 4; ++ns) {
                    u64 p = (((u64)__float_as_uint(dval[ns])) << 32) | (unsigned)row;
                    colBest[ns] = p < colBest[ns] ? p : colBest[ns];
                }
            }
#pragma unroll
            for (int ns = 0; ns < 4; ++ns)
                Cs[(lq * 4 + r) * 64 + ns * 16 + lr] = dval[ns];
        }
        // triangle tile store only (rows of dist)
#pragma unroll
        for (int p = 0; p < 4; ++p) {
            float4 v4 = *(float4*)&Cs[p * 256 + lane * 4];
            const int gr = row0 + wm * 64 + ms * 16 + p * 4 + (lane >> 4);
            const int gc = col0 + wn * 64 + (lane & 15) * 4;
            *(float4*)&dist[(size_t)gr * N + gc] = v4;
        }
    }
    // column argmin -> compBest for the mirror rows (off-diagonal only)
    if (!diag) {
#pragma unroll
        for (int ns = 0; ns < 4; ++ns) {
            u64 b = colBest[ns];
            u64 o = __shfl_xor(b, 16, 64);
            b = o < b ? o : b;
            o = __shfl_xor(b, 32, 64);
            b = o < b ? o : b;
            if (lq == 0) atomicMin(&cb[col0 + wn * 64 + ns * 16 + lr], b);
        }
    }
}

// ---------------- merge round 1 (blocks 0,1) + distc +inf init (blocks 2..1025)
__global__ __launch_bounds__(1024) void merge1i_kernel(int* __restrict__ comp,
                                                       u64* __restrict__ compBest,
                                                       float* __restrict__ deaths,
                                                       int* __restrict__ cnt,
                                                       int* __restrict__ numComp,
                                                       int* __restrict__ numC1,
                                                       unsigned* __restrict__ distc_u) {
    const int t = threadIdx.x;
    if (blockIdx.x >= 2) {
        const size_t idx = (size_t)(blockIdx.x - 2) * 1024 + t;
        uint4 v = make_uint4(0x7f800000u, 0x7f800000u, 0x7f800000u, 0x7f800000u);
        ((uint4*)distc_u)[idx] = v;
        ((uint4*)distc_u)[idx + 1048576] = v;
        return;
    }
    const int m = blockIdx.x;
    int* cp = comp + (size_t)m * N;
    u64* cb = compBest + (size_t)m * N;
    float* dth = deaths + (size_t)m * N;

    __shared__ int pa[N];
    __shared__ int pb[N];
    __shared__ unsigned flagbits[NW];
    __shared__ int wpc[NW];
    __shared__ int done;

    if (t == 0) cnt[m] = 0;
    __syncthreads();

    for (int c = t; c < N; c += 1024) {
        u64 best = cb[c];
        int p = c;
        if (best != ~0ull) {
            int j = (int)(unsigned)best;
            int c2 = cp[j];
            u64 best2 = cb[c2];
            int j2 = (int)(unsigned)best2;
            bool mutual = (cp[j2] == c);
            if (!(mutual && c < c2)) {
                p = c2;
                int idx = atomicAdd(cnt + m, 1);
                dth[idx] = __uint_as_float((unsigned)(best >> 32));
            }
        }
        pa[c] = p;
    }

    int* A = pa;
    int* B = pb;
    while (true) {
        __syncthreads();
        if (t == 0) done = 1;
        __syncthreads();
        bool ch = false;
        for (int c = t; c < N; c += 1024) {
            int g = A[A[c]];
            B[c] = g;
            ch |= (g != A[c]);
        }
        if (ch) done = 0;
        __syncthreads();
        int* tmp = A; A = B; B = tmp;
        if (done) break;
    }

    for (int w = t; w < NW; w += 1024) flagbits[w] = 0u;
    __syncthreads();
    for (int i = t; i < N; i += 1024)
        atomicOr(&flagbits[A[i] >> 5], 1u << (A[i] & 31));
    __syncthreads();
    if (t < NW) wpc[t] = __popc(flagbits[t]);
    __syncthreads();
    for (int off = 1; off < NW; off <<= 1) {
        int v = 0;
        if (t < NW) v = wpc[t] + ((t >= off) ? wpc[t - off] : 0);
        __syncthreads();
        if (t < NW) wpc[t] = v;
        __syncthreads();
    }
    for (int i = t; i < N; i += 1024) {
        int root = A[i];
        int w = root >> 5, b = root & 31;
        int base = w ? wpc[w - 1] : 0;
        unsigned mask = b ? ((1u << b) - 1u) : 0u;
        cp[i] = base + __popc(flagbits[w] & mask);
    }
    for (int c = t; c < N; c += 1024) cb[c] = ~0ull;
    if (t == 0) {
        int C1 = wpc[NW - 1];
        numC1[m] = C1;
        numComp[m] = C1;
    }
}

// ---------------- atomic level-1 contraction, TRIANGLE reads only.
// One block per row (full parallelism — R5 lesson: never serialize rows per block).
// LDS bins restricted to ceil64(C1); flush via global atomicMin.
__global__ __launch_bounds__(256) void rowatomic_kernel(const float* __restrict__ dist1,
                                                        const float* __restrict__ dist2,
                                                        const int* __restrict__ comp,
                                                        const int* __restrict__ numC1,
                                                        unsigned* __restrict__ distc_u) {
    const int m = blockIdx.y;
    const int cend = (numC1[m] + 63) & ~63;
    const float* dist = m ? dist2 : dist1;
    const int* cp = comp + (size_t)m * N;
    const int i = blockIdx.x;
    const float4* row4 = (const float4*)(dist + (size_t)i * N);
    const int4* cp4 = (const int4*)cp;
    __shared__ unsigned bins[CMAX];
    const int t = threadIdx.x;
    for (int b = t; b < cend; b += 256) bins[b] = 0x7f800000u;
    __syncthreads();
    const int q0 = (i >> 7) << 5;   // float4 index of this row's diagonal-tile start
    for (int q = q0 + t; q < N / 4; q += 256) {
        float4 v = row4[q];
        int4 cj = cp4[q];
        atomicMin(&bins[cj.x], __float_as_uint(v.x));
        atomicMin(&bins[cj.y], __float_as_uint(v.y));
        atomicMin(&bins[cj.z], __float_as_uint(v.z));
        atomicMin(&bins[cj.w], __float_as_uint(v.w));
    }
    __syncthreads();
    unsigned* drow = distc_u + ((size_t)m * CMAX + cp[i]) * CMAX;
    for (int b = t; b < cend; b += 256) {
        unsigned v = bins[b];
        if (v != 0x7f800000u) atomicMin(&drow[b], v);
    }
}

// ---------------- FUSED symmetrize + round-2 scan + distc2 init
#define CT 64
#define NCT (CMAX / CT)                // 32
#define NPAIRC (NCT * (NCT + 1) / 2)   // 528
__global__ __launch_bounds__(256) void symscan_kernel(unsigned* __restrict__ distc_u,
                                                      u64* __restrict__ compBest,
                                                      const int* __restrict__ numComp,
                                                      const int* __restrict__ numC1,
                                                      unsigned* __restrict__ distc2_u) {
    const int tid = threadIdx.x;
    if (blockIdx.x >= NPAIRC) {
        // init distc2: 2*CMAX2*CMAX2 floats = 524,288 uint4; (256 blocks x 2 y) x 256 thr x 4
        const size_t base = ((size_t)blockIdx.y * 256 + (blockIdx.x - NPAIRC)) * 256 + tid;
        uint4 v = make_uint4(0x7f800000u, 0x7f800000u, 0x7f800000u, 0x7f800000u);
#pragma unroll
        for (int k = 0; k < 4; ++k)
            ((uint4*)distc2_u)[base + (size_t)k * 131072] = v;
        return;
    }
    const int m = blockIdx.y;
    if (numComp[m] <= 1) return;
    const int C1 = numC1[m];
    const int t = blockIdx.x;
    int a = (int)((65.0f - sqrtf(4225.0f - 8.0f * (float)t)) * 0.5f);
    while (a > 0 && a * 32 - a * (a - 1) / 2 > t) --a;
    while ((a + 1) * 32 - (a + 1) * a / 2 <= t) ++a;
    const int b = a + (t - (a * 32 - a * (a - 1) / 2));
    if (a * CT >= C1 || b * CT >= C1) return;   // all-inf region, never read downstream

    unsigned* Dm = distc_u + (size_t)m * CMAX * CMAX;
    unsigned* P = Dm + (size_t)(a * CT) * CMAX + b * CT;   // tile (a,b)
    unsigned* Q = Dm + (size_t)(b * CT) * CMAX + a * CT;   // tile (b,a)
    u64* cb = compBest + (size_t)m * N;

    __shared__ float L[CT][CT + 1];
    __shared__ float M[CT][CT + 1];
#pragma unroll
    for (int e0 = 0; e0 < 4; ++e0) {
        int e = e0 * 256 + tid;
        int r = e >> 4, c4 = (e & 15) << 2;
        float4 v = *(const float4*)&Q[(size_t)r * CMAX + c4];
        L[r][c4] = v.x; L[r][c4 + 1] = v.y; L[r][c4 + 2] = v.z; L[r][c4 + 3] = v.w;
    }
    __syncthreads();
#pragma unroll
    for (int e0 = 0; e0 < 4; ++e0) {
        int e = e0 * 256 + tid;
        int r = e >> 4, c4 = (e & 15) << 2;
        float4 v = *(const float4*)&P[(size_t)r * CMAX + c4];
        float4 f;
        f.x = fminf(v.x, L[c4 + 0][r]);
        f.y = fminf(v.y, L[c4 + 1][r]);
        f.z = fminf(v.z, L[c4 + 2][r]);
        f.w = fminf(v.w, L[c4 + 3][r]);
        *(float4*)&P[(size_t)r * CMAX + c4] = f;
        M[r][c4] = f.x; M[r][c4 + 1] = f.y; M[r][c4 + 2] = f.z; M[r][c4 + 3] = f.w;
    }
    __syncthreads();

    // direction 1: rows of tile a over cols of tile b (S rows)
    {
        const int rloc = tid >> 2;
        const int r = a * CT + rloc;
        const int c0 = (tid & 3) * 16;
        u64 best = ~0ull;
#pragma unroll
        for (int c = 0; c < 16; ++c) {
            const int j = b * CT + c0 + c;
            const unsigned bits = __float_as_uint(M[rloc][c0 + c]);
            if (j < C1 && j != r && bits < 0x7f800000u) {
                u64 p = (((u64)bits) << 32) | (unsigned)j;
                best = p < best ? p : best;
            }
        }
        u64 o = __shfl_xor(best, 1, 64); best = o < best ? o : best;
        o = __shfl_xor(best, 2, 64); best = o < best ? o : best;
        if ((tid & 3) == 0 && r < C1 && best != ~0ull) atomicMin(&cb[r], best);
    }

    if (a == b) return;

    // direction 2: rows of tile b over cols of tile a (S^T = M columns)
    {
        const int rloc = tid >> 2;
        const int r = b * CT + rloc;
        const int c0 = (tid & 3) * 16;
        u64 best = ~0ull;
#pragma unroll
        for (int c = 0; c < 16; ++c) {
            const int j = a * CT + c0 + c;
            const unsigned bits = __float_as_uint(M[c0 + c][rloc]);
            if (j < C1 && bits < 0x7f800000u) {   // j != r guaranteed (a != b)
                u64 p = (((u64)bits) << 32) | (unsigned)j;
                best = p < best ? p : best;
            }
        }
        u64 o = __shfl_xor(best, 1, 64); best = o < best ? o : best;
        o = __shfl_xor(best, 2, 64); best = o < best ? o : best;
        if ((tid & 3) == 0 && r < C1 && best != ~0ull) atomicMin(&cb[r], best);
    }

    // write back S^T to tile (b,a)
#pragma unroll
    for (int e0 = 0; e0 < 4; ++e0) {
        int e = e0 * 256 + tid;
        int r = e >> 4, c4 = (e & 15) << 2;
        float4 f;
        f.x = M[c4 + 0][r];
        f.y = M[c4 + 1][r];
        f.z = M[c4 + 2][r];
        f.w = M[c4 + 3][r];
        *(float4*)&Q[(size_t)r * CMAX + c4] = f;
    }
}

// ---------------- merge round 2 (trimmed): hook + jump + dense relabel + comp_c2 identity
__global__ __launch_bounds__(1024) void merge2_kernel(int* __restrict__ comp_c,
                                                      u64* __restrict__ compBest,
                                                      float* __restrict__ deaths,
                                                      int* __restrict__ cnt,
                                                      int* __restrict__ numComp,
                                                      const int* __restrict__ numC1,
                                                      int* __restrict__ numC2,
                                                      int* __restrict__ comp_c2) {
    const int m = blockIdx.x;
    const int t = threadIdx.x;
    const int C1 = numC1[m];
    int* cc2i = comp_c2 + (size_t)m * CMAX2;
    for (int c = t; c < CMAX2; c += 1024) cc2i[c] = c;
    if (numComp[m] <= 1) {
        if (t == 0) numC2[m] = numComp[m];
        return;
    }
    int* cc = comp_c + (size_t)m * CMAX;
    u64* cb = compBest + (size_t)m * N;
    float* dth = deaths + (size_t)m * N;

    __shared__ int pa[CMAX];
    __shared__ int pb[CMAX];
    __shared__ unsigned flagbits[CMAX / 32];
    __shared__ int wpc[CMAX / 32];
    __shared__ int done;

    for (int c = t; c < C1; c += 1024) {
        u64 best = cb[c];
        int p = c;
        if (best != ~0ull) {
            int j = (int)(unsigned)best;
            int c2 = cc[j];
            u64 best2 = cb[c2];
            int j2 = (int)(unsigned)best2;
            bool mutual = (cc[j2] == c);
            if (!(mutual && c < c2)) {
                p = c2;
                int idx = atomicAdd(cnt + m, 1);
                dth[idx] = __uint_as_float((unsigned)(best >> 32));
            }
        }
        pa[c] = p;
    }

    int* A = pa;
    int* B = pb;
    while (true) {
        __syncthreads();
        if (t == 0) done = 1;
        __syncthreads();
        bool ch = false;
        for (int c = t; c < C1; c += 1024) {
            int g = A[A[c]];
            B[c] = g;
            ch |= (g != A[c]);
        }
        if (ch) done = 0;
        __syncthreads();
        int* tmp = A; A = B; B = tmp;
        if (done) break;
    }

    for (int w = t; w < CMAX / 32; w += 1024) flagbits[w] = 0u;
    __syncthreads();
    for (int j = t; j < C1; j += 1024)
        atomicOr(&flagbits[A[j] >> 5], 1u << (A[j] & 31));
    __syncthreads();
    if (t < CMAX / 32) wpc[t] = __popc(flagbits[t]);
    __syncthreads();
    for (int off = 1; off < CMAX / 32; off <<= 1) {
        int v = 0;
        if (t < CMAX / 32) v = wpc[t] + ((t >= off) ? wpc[t - off] : 0);
        __syncthreads();
        if (t < CMAX / 32) wpc[t] = v;
        __syncthreads();
    }
    for (int j = t; j < C1; j += 1024) {
        int root = A[j];
        int w = root >> 5, b = root & 31;
        int base = w ? wpc[w - 1] : 0;
        unsigned mask = b ? ((1u << b) - 1u) : 0u;
        cc[j] = base + __popc(flagbits[w] & mask);
    }
    for (int c = t; c < C1; c += 1024) cb[c] = ~0ull;
    if (t == 0) {
        int C2 = wpc[CMAX / 32 - 1];
        numC2[m] = C2;
        numComp[m] = C2;
    }
}

// ---------------- atomic level-2 contraction: row of distc -> bins[C2] -> distc2
__global__ __launch_bounds__(256) void rowatomic2_kernel(const float* __restrict__ distc,
                                                         const int* __restrict__ comp_c,
                                                         const int* __restrict__ numComp,
                                                         const int* __restrict__ numC1,
                                                         unsigned* __restrict__ distc2_u) {
    const int m = blockIdx.y;
    if (numComp[m] <= 1) return;
    const int C1 = numC1[m];
    const int r = blockIdx.x;
    if (r >= C1) return;
    const int* cc = comp_c + (size_t)m * CMAX;
    const float* row = distc + ((size_t)m * CMAX + r) * CMAX;
    __shared__ unsigned bins[CMAX2];
    const int t = threadIdx.x;
    for (int b = t; b < CMAX2; b += 256) bins[b] = 0x7f800000u;
    __syncthreads();
    for (int j = t; j < C1; j += 256)
        atomicMin(&bins[cc[j]], __float_as_uint(row[j]));
    __syncthreads();
    unsigned* drow = distc2_u + ((size_t)m * CMAX2 + cc[r]) * CMAX2;
    for (int b = t; b < CMAX2; b += 256) {
        unsigned v = bins[b];
        if (v != 0x7f800000u) atomicMin(&drow[b], v);
    }
}

// ---------------- level-3 scan over distc2 (blocks < 2*CMAX2) + distc3 +inf init (rest)
__global__ __launch_bounds__(256) void scan3_kernel(const float* __restrict__ distc2,
                                                    const int* __restrict__ comp_c2,
                                                    u64* __restrict__ compBest,
                                                    const int* __restrict__ numComp,
                                                    const int* __restrict__ numC2,
                                                    unsigned* __restrict__ distc3_u) {
    const int t = threadIdx.x;
    if (blockIdx.x >= 2 * CMAX2) {
        // init distc3: 2*512*512 floats = 131072 uint4; 256 blocks x 256 thr x 2
        const size_t idx = (size_t)(blockIdx.x - 2 * CMAX2) * 256 + t;
        uint4 v = make_uint4(0x7f800000u, 0x7f800000u, 0x7f800000u, 0x7f800000u);
        ((uint4*)distc3_u)[idx] = v;
        ((uint4*)distc3_u)[idx + 65536] = v;
        return;
    }
    const int m = blockIdx.x >> 10;          // CMAX2 = 1024
    if (numComp[m] <= 1) return;
    const int C2 = numC2[m];
    const int r = blockIdx.x & (CMAX2 - 1);
    if (r >= C2) return;
    const int* cc = comp_c2 + (size_t)m * CMAX2;
    u64* cb = compBest + (size_t)m * N;
    const int myc = cc[r];
    const float4* row4 = (const float4*)(distc2 + ((size_t)m * CMAX2 + r) * CMAX2);
    const int4* cc4 = (const int4*)cc;
    float4 v = row4[t];
    int4 cj = cc4[t];
    int j0 = t * 4;
    u64 p0 = (j0 + 0 < C2 && cj.x != myc) ? ((((u64)__float_as_uint(v.x)) << 32) | (unsigned)(j0 + 0)) : ~0ull;
    u64 p1 = (j0 + 1 < C2 && cj.y != myc) ? ((((u64)__float_as_uint(v.y)) << 32) | (unsigned)(j0 + 1)) : ~0ull;
    u64 p2 = (j0 + 2 < C2 && cj.z != myc) ? ((((u64)__float_as_uint(v.z)) << 32) | (unsigned)(j0 + 2)) : ~0ull;
    u64 p3 = (j0 + 3 < C2 && cj.w != myc) ? ((((u64)__float_as_uint(v.w)) << 32) | (unsigned)(j0 + 3)) : ~0ull;
    u64 q0 = p0 < p1 ? p0 : p1;
    u64 q1 = p2 < p3 ? p2 : p3;
    u64 best = q0 < q1 ? q0 : q1;
#pragma unroll
    for (int off = 32; off > 0; off >>= 1) {
        u64 o = __shfl_down(best, off, 64);
        best = o < best ? o : best;
    }
    if ((t & 63) == 0) atomicMin(cb + myc, best);
}

// ---------------- merge round 3: hook + jump + dense relabel of comp_c2
__global__ __launch_bounds__(1024) void merge3_kernel(int* __restrict__ comp_c2,
                                                      u64* __restrict__ compBest,
                                                      float* __restrict__ deaths,
                                                      int* __restrict__ cnt,
                                                      int* __restrict__ numComp,
                                                      const int* __restrict__ numC2,
                                                      int* __restrict__ numC3) {
    const int m = blockIdx.x;
    const int t = threadIdx.x;
    if (numComp[m] <= 1) {
        if (t == 0) numC3[m] = numComp[m];
        return;
    }
    const int C2 = numC2[m];
    int* cc = comp_c2 + (size_t)m * CMAX2;
    u64* cb = compBest + (size_t)m * N;
    float* dth = deaths + (size_t)m * N;

    __shared__ int pa[CMAX2];
    __shared__ int pb[CMAX2];
    __shared__ unsigned flagbits[CMAX2 / 32];
    __shared__ int wpc[CMAX2 / 32];
    __shared__ int done;

    for (int c = t; c < C2; c += 1024) {
        u64 best = cb[c];
        int p = c;
        if (best != ~0ull) {
            int j = (int)(unsigned)best;
            int c2 = cc[j];
            u64 best2 = cb[c2];
            int j2 = (int)(unsigned)best2;
            bool mutual = (cc[j2] == c);
            if (!(mutual && c < c2)) {
                p = c2;
                int idx = atomicAdd(cnt + m, 1);
                dth[idx] = __uint_as_float((unsigned)(best >> 32));
            }
        }
        pa[c] = p;
    }

    int* A = pa;
    int* B = pb;
    while (true) {
        __syncthreads();
        if (t == 0) done = 1;
        __syncthreads();
        bool ch = false;
        for (int c = t; c < C2; c += 1024) {
            int g = A[A[c]];
            B[c] = g;
            ch |= (g != A[c]);
        }
        if (ch) done = 0;
        __syncthreads();
        int* tmp = A; A = B; B = tmp;
        if (done) break;
    }

    for (int w = t; w < CMAX2 / 32; w += 1024) flagbits[w] = 0u;
    __syncthreads();
    for (int j = t; j < C2; j += 1024)
        atomicOr(&flagbits[A[j] >> 5], 1u << (A[j] & 31));
    __syncthreads();
    if (t < CMAX2 / 32) wpc[t] = __popc(flagbits[t]);
    __syncthreads();
    for (int off = 1; off < CMAX2 / 32; off <<= 1) {
        int v = 0;
        if (t < CMAX2 / 32) v = wpc[t] + ((t >= off) ? wpc[t - off] : 0);
        __syncthreads();
        if (t < CMAX2 / 32) wpc[t] = v;
        __syncthreads();
    }
    for (int j = t; j < C2; j += 1024) {
        int root = A[j];
        int w = root >> 5, b = root & 31;
        int base = w ? wpc[w - 1] : 0;
        unsigned mask = b ? ((1u << b) - 1u) : 0u;
        cc[j] = base + __popc(flagbits[w] & mask);
    }
    for (int c = t; c < C2; c += 1024) cb[c] = ~0ull;
    if (t == 0) {
        int C3 = wpc[CMAX2 / 32 - 1];
        numC3[m] = C3;
        numComp[m] = C3;
    }
}

// ---------------- atomic level-3 contraction: row of distc2 -> bins[C3] -> distc3
__global__ __launch_bounds__(256) void rowatomic3_kernel(const float* __restrict__ distc2,
                                                         const int* __restrict__ comp_c2,
                                                         const int* __restrict__ numComp,
                                                         const int* __restrict__ numC2,
                                                         unsigned* __restrict__ distc3_u) {
    const int m = blockIdx.y;
    if (numComp[m] <= 1) return;
    const int C2 = numC2[m];
    const int r = blockIdx.x;
    if (r >= C2) return;
    const int* cc = comp_c2 + (size_t)m * CMAX2;
    const float* row = distc2 + ((size_t)m * CMAX2 + r) * CMAX2;
    __shared__ unsigned bins[CMAX3];
    const int t = threadIdx.x;
    for (int b = t; b < CMAX3; b += 256) bins[b] = 0x7f800000u;
    __syncthreads();
    for (int j = t; j < C2; j += 256)
        atomicMin(&bins[cc[j]], __float_as_uint(row[j]));
    __syncthreads();
    unsigned* drow = distc3_u + ((size_t)m * CMAX3 + cc[r]) * CMAX3;
    for (int b = t; b < CMAX3; b += 256) {
        unsigned v = bins[b];
        if (v != 0x7f800000u) atomicMin(&drow[b], v);
    }
}

// ---------------- finish: rounds >= 4 on distc3 + register-bitonic sort + fused final
__global__ __launch_bounds__(1024) void finish_kernel(const float* __restrict__ distc3,
                                                      float* __restrict__ deaths,
                                                      int* __restrict__ cnt,
                                                      int* __restrict__ numComp,
                                                      const int* __restrict__ numC3,
                                                      const float* __restrict__ accumArr,
                                                      int* __restrict__ doneFlag,
                                                      float* __restrict__ out) {
    const int m = blockIdx.x;
    int nc = numComp[m];
    const int C3 = numC3[m];
    const float* Dm = distc3 + (size_t)m * CMAX3 * CMAX3;
    float* dth = deaths + (size_t)m * N;
    const int t = threadIdx.x;
    const int wave = t >> 6, lane = t & 63;
    __shared__ int comp[CMAX3];
    __shared__ u64 cb[CMAX3];
    __shared__ int pa[CMAX3];
    __shared__ int pb[CMAX3];
    __shared__ unsigned flags[CMAX3 / 32];
    __shared__ int done, ncs, lastf;
    __shared__ float s[N];
    __shared__ float wsum[16];
    __shared__ float rsum[16];

    if (nc > 1) {
        for (int c = t; c < C3; c += 1024) {
            comp[c] = c;
            cb[c] = ~0ull;
        }
        __syncthreads();

        for (int round = 0; round < 10 && nc > 1; ++round) {
            for (int r = wave; r < C3; r += 16) {
                const int myc = comp[r];
                const float* row = Dm + (size_t)r * CMAX3;
                u64 best = ~0ull;
                for (int j = lane; j < C3; j += 64) {
                    if (comp[j] != myc) {
                        u64 p = (((u64)__float_as_uint(row[j])) << 32) | (unsigned)j;
                        best = p < best ? p : best;
                    }
                }
#pragma unroll
                for (int off = 32; off > 0; off >>= 1) {
                    u64 o = __shfl_down(best, off, 64);
                    best = o < best ? o : best;
                }
                if (lane == 0) atomicMin(&cb[myc], best);
            }
            __syncthreads();
            for (int c = t; c < C3; c += 1024) {
                u64 best = cb[c];
                int p = c;
                if (best != ~0ull) {
                    int j = (int)(unsigned)best;
                    int c2 = comp[j];
                    u64 best2 = cb[c2];
                    int j2 = (int)(unsigned)best2;
                    bool mutual = (comp[j2] == c);
                    if (!(mutual && c < c2)) {
                        p = c2;
                        int idx = atomicAdd(cnt + m, 1);
                        dth[idx] = __uint_as_float((unsigned)(best >> 32));
                    }
                }
                pa[c] = p;
            }
            int* A = pa; int* B = pb;
            while (true) {
                __syncthreads();
                if (t == 0) done = 1;
                __syncthreads();
                bool ch = false;
                for (int c = t; c < C3; c += 1024) {
                    int g = A[A[c]];
                    B[c] = g;
                    ch |= (g != A[c]);
                }
                if (ch) done = 0;
                __syncthreads();
                int* tmp = A; A = B; B = tmp;
                if (done) break;
            }
            for (int w = t; w < CMAX3 / 32; w += 1024) flags[w] = 0u;
            __syncthreads();
            for (int j = t; j < C3; j += 1024) {
                int root = A[comp[j]];
                comp[j] = root;
                atomicOr(&flags[root >> 5], 1u << (root & 31));
            }
            for (int c = t; c < C3; c += 1024) cb[c] = ~0ull;
            __syncthreads();
            if (t == 0) {
                int sacc = 0;
                for (int w = 0; w < CMAX3 / 32; ++w) sacc += __popc(flags[w]);
                ncs = sacc;
            }
            __syncthreads();
            nc = ncs;
        }
        if (t == 0) numComp[m] = nc;
    }
    __syncthreads();

    // ---- register-resident bitonic sort (ascending) of the 4096 deaths.
    const int t4 = t << 2;
    float v0, v1, v2, v3;
    {
        float4 l4 = *(const float4*)&dth[t4];
        v0 = l4.x; v1 = l4.y; v2 = l4.z; v3 = l4.w;
        if (t == 1023) v3 = BIG;   // element N-1 pad
    }
#define CSWAP(a, b, up)                         \
    {                                           \
        float mn_ = fminf(a, b), mx_ = fmaxf(a, b); \
        a = (up) ? mn_ : mx_;                   \
        b = (up) ? mx_ : mn_;                   \
    }
    for (int k = 2; k <= N; k <<= 1) {
        for (int jj = k >> 1; jj > 0; jj >>= 1) {
            if (jj >= 256) {
                s[t4] = v0; s[t4 + 1] = v1; s[t4 + 2] = v2; s[t4 + 3] = v3;
                __syncthreads();
                const bool up = ((t4 & k) == 0);
                const bool lower = ((t4 & jj) == 0);
                const bool mk = (up == lower);
                float o0 = s[t4 ^ jj], o1 = s[(t4 + 1) ^ jj];
                float o2 = s[(t4 + 2) ^ jj], o3 = s[(t4 + 3) ^ jj];
                v0 = mk ? fminf(v0, o0) : fmaxf(v0, o0);
                v1 = mk ? fminf(v1, o1) : fmaxf(v1, o1);
                v2 = mk ? fminf(v2, o2) : fmaxf(v2, o2);
                v3 = mk ? fminf(v3, o3) : fmaxf(v3, o3);
                __syncthreads();
            } else if (jj >= 4) {
                const int sl = jj >> 2;
                const bool up = ((t4 & k) == 0);
                const bool lower = ((lane & sl) == 0);
                const bool mk = (up == lower);
                float o0 = __shfl_xor(v0, sl, 64);
                float o1 = __shfl_xor(v1, sl, 64);
                float o2 = __shfl_xor(v2, sl, 64);
                float o3 = __shfl_xor(v3, sl, 64);
                v0 = mk ? fminf(v0, o0) : fmaxf(v0, o0);
                v1 = mk ? fminf(v1, o1) : fmaxf(v1, o1);
                v2 = mk ? fminf(v2, o2) : fmaxf(v2, o2);
                v3 = mk ? fminf(v3, o3) : fmaxf(v3, o3);
            } else if (jj == 2) {
                const bool up = ((t4 & k) == 0);
                CSWAP(v0, v2, up);
                CSWAP(v1, v3, up);
            } else {
                const bool u01 = ((t4 & k) == 0);
                const bool u23 = (((t4 + 2) & k) == 0);
                CSWAP(v0, v1, u01);
                CSWAP(v2, v3, u23);
            }
        }
    }
#undef CSWAP
    *(float4*)&dth[t4] = make_float4(v0, v1, v2, v3);

    // last-block fused final (device-scope ticket; grid-order independent)
    __threadfence();
    __syncthreads();
    if (t == 0) lastf = (atomicAdd(doneFlag, 1) == 1) ? 1 : 0;
    __syncthreads();
    if (!lastf) return;
    __threadfence();
    const float* s1 = deaths;
    const float* s2 = deaths + N;
    float sum = 0.f;
    for (int i = t; i < N - 1; i += 1024) {
        float a = s1[i], b = s2[i];
        sum += fminf(fabsf(a - b), 0.5f * (a + b));
    }
    float ra = accumArr[t];
#pragma unroll
    for (int off = 32; off > 0; off >>= 1) {
        sum += __shfl_down(sum, off, 64);
        ra += __shfl_down(ra, off, 64);
    }
    if (lane == 0) { wsum[wave] = sum; rsum[wave] = ra; }
    __syncthreads();
    if (t == 0) {
        float tot = 0.f, rt = 0.f;
        for (int k = 0; k < 16; ++k) { tot += wsum[k]; rt += rsum[k]; }
        out[0] = rt * (1.0f / ((float)N * (float)D)) + tot;
    }
}

extern "C" void kernel_launch(void* const* d_in, const int* in_sizes, int n_in,
                              void* d_out, int out_size, void* d_ws, size_t ws_size,
                              hipStream_t stream) {
    const float* x1 = (const float*)d_in[0];
    const float* x2 = (const float*)d_in[1];
    float* out = (float*)d_out;
    float* ws = (float*)d_ws;

    const size_t nn = (size_t)N * N;
    const size_t cc2 = (size_t)CMAX * CMAX;

    float* dist1 = ws;
    float* dist2 = ws + nn;
    float* distc = ws + 2 * nn;
    u16* h1 = (u16*)distc;                 // alias: dead before merge1i's init overwrites
    u16* h2 = h1 + (size_t)N * D;
    u64* compBest = (u64*)(distc + 2 * cc2);
    int* comp      = (int*)(compBest + 2 * N);
    int* comp_c    = comp + 2 * N;
    float* deaths  = (float*)(comp_c + 2 * CMAX);
    int* cnt       = (int*)(deaths + 2 * N);
    int* numComp   = cnt + 2;
    int* numC1     = numComp + 2;
    int* numC2     = numC1 + 2;
    int* numC3     = numC2 + 2;
    int* doneFlag  = numC3 + 2;
    float* sq      = (float*)(doneFlag + 2);
    float* accumArr = sq + 2 * N;          // 1024 floats
    // level-2 buffers alias dist1 (dead after rowatomic) — distc2 init'd in symscan's
    // extra blocks, comp_c2 in merge2. Level-3 distc3 aliases distc (dead after
    // rowatomic2), init'd in scan3's extra blocks. NEVER earlier.
    float* distc2  = dist1;
    int* comp_c2   = (int*)(distc2 + 2 * (size_t)CMAX2 * CMAX2);
    float* distc3  = distc;

    prep_kernel<<<N / 4, 256, 0, stream>>>(x1, x2, h1, h2, sq, accumArr, comp, compBest,
                                           comp_c, doneFlag);
    gemm_dist_sym_kernel<<<dim3(NPAIR, 1, 2), 256, 0, stream>>>(h1, h2, sq, dist1, dist2, compBest);
    merge1i_kernel<<<2 + 1024, 1024, 0, stream>>>(comp, compBest, deaths, cnt, numComp, numC1,
                                                  (unsigned*)distc);
    rowatomic_kernel<<<dim3(N, 2), 256, 0, stream>>>(dist1, dist2, comp, numC1, (unsigned*)distc);
    symscan_kernel<<<dim3(NPAIRC + 256, 2), 256, 0, stream>>>((unsigned*)distc, compBest,
                                                              numComp, numC1, (unsigned*)distc2);
    merge2_kernel<<<2, 1024, 0, stream>>>(comp_c, compBest, deaths, cnt, numComp, numC1, numC2,
                                          comp_c2);
    rowatomic2_kernel<<<dim3(CMAX, 2), 256, 0, stream>>>(distc, comp_c, numComp, numC1,
                                                         (unsigned*)distc2);
    scan3_kernel<<<2 * CMAX2 + 256, 256, 0, stream>>>(distc2, comp_c2, compBest, numComp, numC2,
                                                      (unsigned*)distc3);
    merge3_kernel<<<2, 1024, 0, stream>>>(comp_c2, compBest, deaths, cnt, numComp, numC2, numC3);
    rowatomic3_kernel<<<dim3(CMAX2, 2), 256, 0, stream>>>(distc2, comp_c2, numComp, numC2,
                                                          (unsigned*)distc3);
    finish_kernel<<<2, 1024, 0, stream>>>(distc3, deaths, cnt, numComp, numC3,
                                          accumArr, doneFlag, out);
}